// Round 13
// baseline (468.742 us; speedup 1.0000x reference)
//
#include <hip/hip_runtime.h>
#include <math.h>

#define NN 50000
#define NE 800000
#define D  256
#define SCB 196  // ceil(NN/256)

typedef unsigned short u16;
typedef __attribute__((ext_vector_type(8))) short short8;
typedef __attribute__((ext_vector_type(8))) unsigned short u16x8;
typedef __attribute__((ext_vector_type(4))) float f32x4;

// f32 -> bf16 round-to-nearest-even
__device__ __forceinline__ u16 f2b(float f) {
    unsigned u = __float_as_uint(f);
    return (u16)((u + 0x7FFFu + ((u >> 16) & 1u)) >> 16);
}
__device__ __forceinline__ float b2f(u16 b) {
    return __uint_as_float(((unsigned)b) << 16);
}

// ---------------- CSR build ----------------
__global__ void degree_kernel(const int* __restrict__ dst, int* __restrict__ deg) {
    int e0 = (blockIdx.x * blockDim.x + threadIdx.x) * 4;
    if (e0 + 3 < NE) {
        int4 d = *(const int4*)&dst[e0];
        atomicAdd(&deg[d.x], 1);
        atomicAdd(&deg[d.y], 1);
        atomicAdd(&deg[d.z], 1);
        atomicAdd(&deg[d.w], 1);
    } else {
        for (int e = e0; e < NE; e++) atomicAdd(&deg[dst[e]], 1);
    }
}

__global__ void scanA_kernel(const int* __restrict__ deg, int* __restrict__ partial) {
    int t = threadIdx.x;
    int i = blockIdx.x * 256 + t;
    int v = (i < NN) ? deg[i] : 0;
#pragma unroll
    for (int o = 32; o; o >>= 1) v += __shfl_xor(v, o);
    __shared__ int sm[4];
    if ((t & 63) == 0) sm[t >> 6] = v;
    __syncthreads();
    if (t == 0) partial[blockIdx.x] = sm[0] + sm[1] + sm[2] + sm[3];
}

__global__ void scanB_kernel(const int* __restrict__ partial, int* __restrict__ base,
                             int* __restrict__ offs) {
    __shared__ int sm[256];
    int t = threadIdx.x;
    int v = (t < SCB) ? partial[t] : 0;
    sm[t] = v;
    __syncthreads();
    for (int off = 1; off < 256; off <<= 1) {
        int u = 0;
        if (t >= off) u = sm[t - off];
        __syncthreads();
        sm[t] += u;
        __syncthreads();
    }
    if (t < SCB) base[t] = sm[t] - v;
    if (t == 255) offs[NN] = sm[255];
}

__global__ void scanC_kernel(const int* __restrict__ deg, const int* __restrict__ base,
                             int* __restrict__ offs, int* __restrict__ cur) {
    __shared__ int sm[256];
    int t = threadIdx.x;
    int i = blockIdx.x * 256 + t;
    int v = (i < NN) ? deg[i] : 0;
    sm[t] = v;
    __syncthreads();
    for (int off = 1; off < 256; off <<= 1) {
        int u = 0;
        if (t >= off) u = sm[t - off];
        __syncthreads();
        sm[t] += u;
        __syncthreads();
    }
    int o = base[blockIdx.x] + sm[t] - v;
    if (i < NN) {
        offs[i] = o;
        cur[i] = o;
    }
}

__global__ void fill_kernel(const int* __restrict__ src, const int* __restrict__ dst,
                            int* __restrict__ cur, int* __restrict__ csr) {
    int e0 = (blockIdx.x * blockDim.x + threadIdx.x) * 4;
    if (e0 + 3 < NE) {
        int4 d = *(const int4*)&dst[e0];
        int4 s = *(const int4*)&src[e0];
        int p0 = atomicAdd(&cur[d.x], 1);
        int p1 = atomicAdd(&cur[d.y], 1);
        int p2 = atomicAdd(&cur[d.z], 1);
        int p3 = atomicAdd(&cur[d.w], 1);
        csr[p0] = s.x;
        csr[p1] = s.y;
        csr[p2] = s.z;
        csr[p3] = s.w;
    } else {
        for (int e = e0; e < NE; e++) {
            int pos = atomicAdd(&cur[dst[e]], 1);
            csr[pos] = src[e];
        }
    }
}

// ---------------- merged x-conv + weight pack ----------------
__global__ void wxconv_kernel(const float* __restrict__ x,
                              const float* __restrict__ W1l, const float* __restrict__ W1r,
                              const float* __restrict__ W2l, const float* __restrict__ W2r,
                              u16* __restrict__ Acat,
                              u16* __restrict__ Wcat1, u16* __restrict__ Wcat2) {
    int b = blockIdx.x;
    if (b < 12500) {
        int idx = b * 256 + threadIdx.x;
        int r = idx >> 6;
        int c4 = (idx & 63) * 4;
        float4 v = *(const float4*)&x[(size_t)r * 256 + c4];
        ushort4 o;
        o.x = f2b(v.x); o.y = f2b(v.y); o.z = f2b(v.z); o.w = f2b(v.w);
        *(ushort4*)&Acat[(size_t)r * 512 + 256 + c4] = o;
    } else {
        int r = b - 12500;
        int j = threadIdx.x;
        Wcat1[r * 512 + j]       = f2b(W1l[r * 256 + j]);
        Wcat1[r * 512 + 256 + j] = f2b(W1r[r * 256 + j]);
        Wcat2[r * 512 + j]       = f2b(W2l[r * 256 + j]);
        Wcat2[r * 512 + 256 + j] = f2b(W2r[r * 256 + j]);
    }
}

// ---------------- mean aggregation: one wave per node, 8 gathers in flight --
__global__ __launch_bounds__(256)
void agg_kernel(const u16* __restrict__ Acat, const int* __restrict__ csr,
                const int* __restrict__ offs, u16* __restrict__ AcatW) {
    int wid = (blockIdx.x * blockDim.x + threadIdx.x) >> 6;
    int lane = threadIdx.x & 63;
    if (wid >= NN) return;
    int beg = offs[wid];
    int end = offs[wid + 1];
    int deg = end - beg;
    int half = lane >> 5;
    int lc = (lane & 31) * 8;
    int mid = beg + ((deg + 1) >> 1);
    int e  = half ? mid : beg;
    int hi = half ? end : mid;
    float a[8] = {0.f, 0.f, 0.f, 0.f, 0.f, 0.f, 0.f, 0.f};
    for (; e + 7 < hi; e += 8) {
        int s0 = csr[e + 0], s1 = csr[e + 1], s2 = csr[e + 2], s3 = csr[e + 3];
        int s4 = csr[e + 4], s5 = csr[e + 5], s6 = csr[e + 6], s7 = csr[e + 7];
        u16x8 v0 = *(const u16x8*)&Acat[(size_t)s0 * 512 + 256 + lc];
        u16x8 v1 = *(const u16x8*)&Acat[(size_t)s1 * 512 + 256 + lc];
        u16x8 v2 = *(const u16x8*)&Acat[(size_t)s2 * 512 + 256 + lc];
        u16x8 v3 = *(const u16x8*)&Acat[(size_t)s3 * 512 + 256 + lc];
        u16x8 v4 = *(const u16x8*)&Acat[(size_t)s4 * 512 + 256 + lc];
        u16x8 v5 = *(const u16x8*)&Acat[(size_t)s5 * 512 + 256 + lc];
        u16x8 v6 = *(const u16x8*)&Acat[(size_t)s6 * 512 + 256 + lc];
        u16x8 v7 = *(const u16x8*)&Acat[(size_t)s7 * 512 + 256 + lc];
#pragma unroll
        for (int i = 0; i < 8; i++)
            a[i] += ((b2f(v0[i]) + b2f(v1[i])) + (b2f(v2[i]) + b2f(v3[i]))) +
                    ((b2f(v4[i]) + b2f(v5[i])) + (b2f(v6[i]) + b2f(v7[i])));
    }
    for (; e + 3 < hi; e += 4) {
        int s0 = csr[e + 0], s1 = csr[e + 1], s2 = csr[e + 2], s3 = csr[e + 3];
        u16x8 v0 = *(const u16x8*)&Acat[(size_t)s0 * 512 + 256 + lc];
        u16x8 v1 = *(const u16x8*)&Acat[(size_t)s1 * 512 + 256 + lc];
        u16x8 v2 = *(const u16x8*)&Acat[(size_t)s2 * 512 + 256 + lc];
        u16x8 v3 = *(const u16x8*)&Acat[(size_t)s3 * 512 + 256 + lc];
#pragma unroll
        for (int i = 0; i < 8; i++)
            a[i] += (b2f(v0[i]) + b2f(v1[i])) + (b2f(v2[i]) + b2f(v3[i]));
    }
    for (; e < hi; e++) {
        int s0 = csr[e];
        u16x8 v0 = *(const u16x8*)&Acat[(size_t)s0 * 512 + 256 + lc];
#pragma unroll
        for (int i = 0; i < 8; i++) a[i] += b2f(v0[i]);
    }
#pragma unroll
    for (int i = 0; i < 8; i++) a[i] += __shfl_xor(a[i], 32);
    float sc = (deg > 0) ? 1.0f / (float)deg : 0.0f;
    if (half == 0) {
        u16x8 o;
#pragma unroll
        for (int i = 0; i < 8; i++) o[i] = f2b(a[i] * sc);
        *(u16x8*)&AcatW[(size_t)wid * 512 + lc] = o;
    }
}

// ---------------- MFMA GEMM: C[NN][256] = A[NN][512] @ W[256][512]^T + bias
// LDS-FREE: each lane loads its MFMA fragments directly global->VGPR.
// Fragment source: lane l reads A[rowbase+(l&15)][k0+(l>>4)*8] (16 rows x 64B
// segments). A-frag reuse across n and B-frag reuse across m happen in
// registers; cross-wave duplicate reads hit L2/L3. No barriers, no LDS
// hazards -- waves fully decoupled, compiler pipelines the unrolled K-loop.
template<int BF16_OUT>
__global__ __launch_bounds__(256)
void mfma_gemm_kernel(const u16* __restrict__ A, const u16* __restrict__ W,
                      const float* __restrict__ bias, void* __restrict__ Cout) {
    const int l = threadIdx.x & 63;
    const int wid = threadIdx.x >> 6;
    const int wr = wid >> 1, wc = wid & 1;
    const int row0 = blockIdx.x * 128;
    const int col0 = blockIdx.y * 128;
    const int fr = l & 15;           // fragment row within 16
    const int ko = (l >> 4) * 8;     // k-offset within a 32-wide K-step

    const u16* aptr[4];
    const u16* bptr[4];
#pragma unroll
    for (int m = 0; m < 4; m++) {
        int ra = row0 + wr * 64 + m * 16 + fr;
        if (ra > NN - 1) ra = NN - 1;
        aptr[m] = A + (size_t)ra * 512 + ko;
    }
#pragma unroll
    for (int n = 0; n < 4; n++)
        bptr[n] = W + (size_t)(col0 + wc * 64 + n * 16 + fr) * 512 + ko;

    f32x4 acc[4][4] = {};
    short8 af[4], bf[4], afn[4], bfn[4];
#pragma unroll
    for (int m = 0; m < 4; m++) af[m] = *(const short8*)(aptr[m]);
#pragma unroll
    for (int n = 0; n < 4; n++) bf[n] = *(const short8*)(bptr[n]);

#pragma unroll
    for (int t = 0; t < 16; t++) {
        if (t < 15) {
#pragma unroll
            for (int m = 0; m < 4; m++)
                afn[m] = *(const short8*)(aptr[m] + (t + 1) * 32);
#pragma unroll
            for (int n = 0; n < 4; n++)
                bfn[n] = *(const short8*)(bptr[n] + (t + 1) * 32);
        }
#pragma unroll
        for (int m = 0; m < 4; m++)
#pragma unroll
            for (int n = 0; n < 4; n++)
                acc[m][n] = __builtin_amdgcn_mfma_f32_16x16x32_bf16(
                    af[m], bf[n], acc[m][n], 0, 0, 0);
#pragma unroll
        for (int m = 0; m < 4; m++) af[m] = afn[m];
#pragma unroll
        for (int n = 0; n < 4; n++) bf[n] = bfn[n];
    }

    // epilogue: C/D layout col = lane&15, row = (lane>>4)*4 + j
    const int cq = l >> 4;
    const int cc = l & 15;
#pragma unroll
    for (int m = 0; m < 4; m++) {
#pragma unroll
        for (int n = 0; n < 4; n++) {
            int c = col0 + wc * 64 + n * 16 + cc;
#pragma unroll
            for (int j = 0; j < 4; j++) {
                int r = row0 + wr * 64 + m * 16 + cq * 4 + j;
                if (r < NN) {
                    float v = acc[m][n][j] + bias[c];
                    if (BF16_OUT)
                        ((u16*)Cout)[(size_t)r * 256 + c] = f2b(v);
                    else
                        ((float*)Cout)[(size_t)r * 256 + c] = v;
                }
            }
        }
    }
}

// ---------------- per-column sum & sumsq for BN (bf16 input) ----------------
__global__ void colstats_kernel(const u16* __restrict__ h, float* __restrict__ stats) {
    int j = threadIdx.x;
    float s0 = 0.f, s1 = 0.f;
    for (int r = blockIdx.x; r < NN; r += gridDim.x) {
        float v = b2f(h[(size_t)r * 256 + j]);
        s0 += v;
        s1 += v * v;
    }
    atomicAdd(&stats[j], s0);
    atomicAdd(&stats[256 + j], s1);
}

// ---------------- BN + ReLU with inlined bnfin ----------------
__global__ void bnrelu_kernel(const u16* __restrict__ hb,
                              const float* __restrict__ stats,
                              const float* __restrict__ gamma,
                              const float* __restrict__ beta,
                              u16* __restrict__ Acat) {
    __shared__ float s_scale[256], s_shift[256];
    int t = threadIdx.x;
    {
        const float invN = 1.0f / (float)NN;
        float mu = stats[t] * invN;
        float var = stats[256 + t] * invN - mu * mu;
        float sc = gamma[t] * rsqrtf(var + 1e-5f);
        s_scale[t] = sc;
        s_shift[t] = beta[t] - mu * sc;
    }
    __syncthreads();
    int idx = blockIdx.x * 256 + t;
    int r = idx >> 5;
    int c8 = (idx & 31) * 8;
    u16x8 v = *(const u16x8*)&hb[(size_t)r * 256 + c8];
    u16x8 o;
#pragma unroll
    for (int i = 0; i < 8; i++) {
        float f = b2f(v[i]) * s_scale[c8 + i] + s_shift[c8 + i];
        o[i] = f2b(fmaxf(f, 0.f));
    }
    *(u16x8*)&Acat[(size_t)r * 512 + 256 + c8] = o;
}

// ---------------- row L2 normalize + fused column-sum ------------------
__global__ __launch_bounds__(512)
void l2norm_kernel(float* __restrict__ out, float* __restrict__ gsum) {
    __shared__ float sm[8 * 256];
    int wave = threadIdx.x >> 6;   // 0..7
    int lane = threadIdx.x & 63;
    float c0 = 0.f, c1 = 0.f, c2 = 0.f, c3 = 0.f;
    for (int r = blockIdx.x * 8 + wave; r < NN; r += gridDim.x * 8) {
        float4 v = *(float4*)&out[(size_t)r * 256 + lane * 4];
        float sq = v.x * v.x + v.y * v.y + v.z * v.z + v.w * v.w;
#pragma unroll
        for (int o = 32; o; o >>= 1) sq += __shfl_xor(sq, o);
        float invn = 1.0f / fmaxf(sqrtf(sq), 1e-12f);
        v.x *= invn; v.y *= invn; v.z *= invn; v.w *= invn;
        *(float4*)&out[(size_t)r * 256 + lane * 4] = v;
        c0 += v.x; c1 += v.y; c2 += v.z; c3 += v.w;
    }
    *(float4*)&sm[wave * 256 + lane * 4] = make_float4(c0, c1, c2, c3);
    __syncthreads();
    int t = threadIdx.x;
    if (t < 256) {
        float s = 0.f;
#pragma unroll
        for (int w = 0; w < 8; w++) s += sm[w * 256 + t];
        atomicAdd(&gsum[t], s);
    }
}

__global__ void graph_kernel(const float* __restrict__ gsum, float* __restrict__ gout) {
    __shared__ float wsum[4];
    int j = threadIdx.x;
    float v = gsum[j] * (1.0f / (float)NN);
    float sq = v * v;
#pragma unroll
    for (int o = 32; o; o >>= 1) sq += __shfl_xor(sq, o);
    if ((j & 63) == 0) wsum[j >> 6] = sq;
    __syncthreads();
    float tot = wsum[0] + wsum[1] + wsum[2] + wsum[3];
    gout[j] = v / fmaxf(sqrtf(tot), 1e-12f);
}

extern "C" void kernel_launch(void* const* d_in, const int* in_sizes, int n_in,
                              void* d_out, int out_size, void* d_ws, size_t ws_size,
                              hipStream_t stream) {
    const float* x      = (const float*)d_in[0];
    const float* W1_l   = (const float*)d_in[1];
    const float* b1_l   = (const float*)d_in[2];
    const float* W1_r   = (const float*)d_in[3];
    const float* W2_l   = (const float*)d_in[4];
    const float* b2_l   = (const float*)d_in[5];
    const float* W2_r   = (const float*)d_in[6];
    const float* gamma1 = (const float*)d_in[7];
    const float* beta1  = (const float*)d_in[8];
    const int*   eidx   = (const int*)d_in[9];
    const int* src = eidx;
    const int* dst = eidx + NE;

    char* wsb = (char*)d_ws;
    int*   deg   = (int*)(wsb + 0);
    int*   offs  = (int*)(wsb + 200000);
    int*   cur   = (int*)(wsb + 400004);
    int*   csr   = (int*)(wsb + 600004);
    int*   part  = (int*)(wsb + 3800064);
    int*   base  = (int*)(wsb + 3801088);
    float* stats = (float*)(wsb + 3802112);
    float* gsum  = (float*)(wsb + 3804160);
    u16*   Wcat1 = (u16*)(wsb + 3807232);
    u16*   Wcat2 = (u16*)(wsb + 4069376);
    u16*   hb    = (u16*)(wsb + 4331520);
    u16*   Acat  = (u16*)(wsb + 29931520);
    float* out   = (float*)d_out;
    float* gout  = out + (size_t)NN * 256;

    hipMemsetAsync(deg, 0, NN * sizeof(int), stream);
    hipMemsetAsync(stats, 0, 3072, stream);  // stats + gsum

    wxconv_kernel<<<12756, 256, 0, stream>>>(x, W1_l, W1_r, W2_l, W2_r,
                                             Acat, Wcat1, Wcat2);

    degree_kernel<<<(NE / 4 + 255) / 256, 256, 0, stream>>>(dst, deg);
    scanA_kernel<<<SCB, 256, 0, stream>>>(deg, part);
    scanB_kernel<<<1, 256, 0, stream>>>(part, base, offs);
    scanC_kernel<<<SCB, 256, 0, stream>>>(deg, base, offs, cur);
    fill_kernel<<<(NE / 4 + 255) / 256, 256, 0, stream>>>(src, dst, cur, csr);

    dim3 ggrid((NN + 127) / 128, 2);

    // layer 1
    agg_kernel<<<12500, 256, 0, stream>>>(Acat, csr, offs, Acat);
    mfma_gemm_kernel<1><<<ggrid, 256, 0, stream>>>(Acat, Wcat1, b1_l, hb);
    colstats_kernel<<<512, 256, 0, stream>>>(hb, stats);
    bnrelu_kernel<<<6250, 256, 0, stream>>>(hb, stats, gamma1, beta1, Acat);

    // layer 2
    agg_kernel<<<12500, 256, 0, stream>>>(Acat, csr, offs, Acat);
    mfma_gemm_kernel<0><<<ggrid, 256, 0, stream>>>(Acat, Wcat2, b2_l, out);

    // outputs
    l2norm_kernel<<<1024, 512, 0, stream>>>(out, gsum);
    graph_kernel<<<1, 256, 0, stream>>>(gsum, gout);
}

// Round 14
// 387.410 us; speedup vs baseline: 1.2099x; 1.2099x over previous
//
#include <hip/hip_runtime.h>
#include <math.h>

#define NN 50000
#define NE 800000
#define D  256
#define SCB 196  // ceil(NN/256)

typedef unsigned short u16;
typedef __attribute__((ext_vector_type(8))) short short8;
typedef __attribute__((ext_vector_type(8))) unsigned short u16x8;
typedef __attribute__((ext_vector_type(4))) float f32x4;

// f32 -> bf16 round-to-nearest-even
__device__ __forceinline__ u16 f2b(float f) {
    unsigned u = __float_as_uint(f);
    return (u16)((u + 0x7FFFu + ((u >> 16) & 1u)) >> 16);
}
__device__ __forceinline__ float b2f(u16 b) {
    return __uint_as_float(((unsigned)b) << 16);
}

// async global->LDS, 16 bytes per lane; LDS dest = wave-uniform base + lane*16
__device__ __forceinline__ void gl16(const u16* g, u16* l) {
    __builtin_amdgcn_global_load_lds(
        (const __attribute__((address_space(1))) void*)g,
        (__attribute__((address_space(3))) void*)l, 16, 0, 0);
}

// ---------------- merged x-conv + weight pack + degree count ----------------
// b < 12500: x -> Acat right half (bf16);  12500..12755: weight pack;
// b >= 12756: degree histogram (4 edges/thread, independent atomics).
__global__ void wxconv_kernel(const float* __restrict__ x,
                              const float* __restrict__ W1l, const float* __restrict__ W1r,
                              const float* __restrict__ W2l, const float* __restrict__ W2r,
                              const int* __restrict__ dst,
                              u16* __restrict__ Acat,
                              u16* __restrict__ Wcat1, u16* __restrict__ Wcat2,
                              int* __restrict__ deg) {
    int b = blockIdx.x;
    if (b < 12500) {
        int idx = b * 256 + threadIdx.x;
        int r = idx >> 6;
        int c4 = (idx & 63) * 4;
        float4 v = *(const float4*)&x[(size_t)r * 256 + c4];
        ushort4 o;
        o.x = f2b(v.x); o.y = f2b(v.y); o.z = f2b(v.z); o.w = f2b(v.w);
        *(ushort4*)&Acat[(size_t)r * 512 + 256 + c4] = o;
    } else if (b < 12756) {
        int r = b - 12500;
        int j = threadIdx.x;
        Wcat1[r * 512 + j]       = f2b(W1l[r * 256 + j]);
        Wcat1[r * 512 + 256 + j] = f2b(W1r[r * 256 + j]);
        Wcat2[r * 512 + j]       = f2b(W2l[r * 256 + j]);
        Wcat2[r * 512 + 256 + j] = f2b(W2r[r * 256 + j]);
    } else {
        int e0 = ((b - 12756) * 256 + threadIdx.x) * 4;
        if (e0 + 3 < NE) {
            int4 d = *(const int4*)&dst[e0];
            atomicAdd(&deg[d.x], 1);
            atomicAdd(&deg[d.y], 1);
            atomicAdd(&deg[d.z], 1);
            atomicAdd(&deg[d.w], 1);
        } else {
            for (int e = e0; e < NE; e++) atomicAdd(&deg[dst[e]], 1);
        }
    }
}

// ---------------- CSR scan ----------------
__global__ void scanA_kernel(const int* __restrict__ deg, int* __restrict__ partial) {
    int t = threadIdx.x;
    int i = blockIdx.x * 256 + t;
    int v = (i < NN) ? deg[i] : 0;
#pragma unroll
    for (int o = 32; o; o >>= 1) v += __shfl_xor(v, o);
    __shared__ int sm[4];
    if ((t & 63) == 0) sm[t >> 6] = v;
    __syncthreads();
    if (t == 0) partial[blockIdx.x] = sm[0] + sm[1] + sm[2] + sm[3];
}

__global__ void scanB_kernel(const int* __restrict__ partial, int* __restrict__ base,
                             int* __restrict__ offs) {
    __shared__ int sm[256];
    int t = threadIdx.x;
    int v = (t < SCB) ? partial[t] : 0;
    sm[t] = v;
    __syncthreads();
    for (int off = 1; off < 256; off <<= 1) {
        int u = 0;
        if (t >= off) u = sm[t - off];
        __syncthreads();
        sm[t] += u;
        __syncthreads();
    }
    if (t < SCB) base[t] = sm[t] - v;
    if (t == 255) offs[NN] = sm[255];
}

__global__ void scanC_kernel(const int* __restrict__ deg, const int* __restrict__ base,
                             int* __restrict__ offs, int* __restrict__ cur) {
    __shared__ int sm[256];
    int t = threadIdx.x;
    int i = blockIdx.x * 256 + t;
    int v = (i < NN) ? deg[i] : 0;
    sm[t] = v;
    __syncthreads();
    for (int off = 1; off < 256; off <<= 1) {
        int u = 0;
        if (t >= off) u = sm[t - off];
        __syncthreads();
        sm[t] += u;
        __syncthreads();
    }
    int o = base[blockIdx.x] + sm[t] - v;
    if (i < NN) {
        offs[i] = o;
        cur[i] = o;
    }
}

// 8 edges per thread: int4 x2 loads, 8 independent atomic+store chains
__global__ void fill_kernel(const int* __restrict__ src, const int* __restrict__ dst,
                            int* __restrict__ cur, int* __restrict__ csr) {
    int e0 = (blockIdx.x * blockDim.x + threadIdx.x) * 8;
    if (e0 + 7 < NE) {
        int4 d0 = *(const int4*)&dst[e0];
        int4 d1 = *(const int4*)&dst[e0 + 4];
        int4 s0 = *(const int4*)&src[e0];
        int4 s1 = *(const int4*)&src[e0 + 4];
        int p0 = atomicAdd(&cur[d0.x], 1);
        int p1 = atomicAdd(&cur[d0.y], 1);
        int p2 = atomicAdd(&cur[d0.z], 1);
        int p3 = atomicAdd(&cur[d0.w], 1);
        int p4 = atomicAdd(&cur[d1.x], 1);
        int p5 = atomicAdd(&cur[d1.y], 1);
        int p6 = atomicAdd(&cur[d1.z], 1);
        int p7 = atomicAdd(&cur[d1.w], 1);
        csr[p0] = s0.x; csr[p1] = s0.y; csr[p2] = s0.z; csr[p3] = s0.w;
        csr[p4] = s1.x; csr[p5] = s1.y; csr[p6] = s1.z; csr[p7] = s1.w;
    } else {
        for (int e = e0; e < NE; e++) {
            int pos = atomicAdd(&cur[dst[e]], 1);
            csr[pos] = src[e];
        }
    }
}

// ---------------- mean aggregation: one wave per node, 8 gathers in flight --
__global__ __launch_bounds__(256)
void agg_kernel(const u16* __restrict__ Acat, const int* __restrict__ csr,
                const int* __restrict__ offs, u16* __restrict__ AcatW) {
    int wid = (blockIdx.x * blockDim.x + threadIdx.x) >> 6;
    int lane = threadIdx.x & 63;
    if (wid >= NN) return;
    int beg = offs[wid];
    int end = offs[wid + 1];
    int deg = end - beg;
    int half = lane >> 5;
    int lc = (lane & 31) * 8;
    int mid = beg + ((deg + 1) >> 1);
    int e  = half ? mid : beg;
    int hi = half ? end : mid;
    float a[8] = {0.f, 0.f, 0.f, 0.f, 0.f, 0.f, 0.f, 0.f};
    for (; e + 7 < hi; e += 8) {
        int s0 = csr[e + 0], s1 = csr[e + 1], s2 = csr[e + 2], s3 = csr[e + 3];
        int s4 = csr[e + 4], s5 = csr[e + 5], s6 = csr[e + 6], s7 = csr[e + 7];
        u16x8 v0 = *(const u16x8*)&Acat[(size_t)s0 * 512 + 256 + lc];
        u16x8 v1 = *(const u16x8*)&Acat[(size_t)s1 * 512 + 256 + lc];
        u16x8 v2 = *(const u16x8*)&Acat[(size_t)s2 * 512 + 256 + lc];
        u16x8 v3 = *(const u16x8*)&Acat[(size_t)s3 * 512 + 256 + lc];
        u16x8 v4 = *(const u16x8*)&Acat[(size_t)s4 * 512 + 256 + lc];
        u16x8 v5 = *(const u16x8*)&Acat[(size_t)s5 * 512 + 256 + lc];
        u16x8 v6 = *(const u16x8*)&Acat[(size_t)s6 * 512 + 256 + lc];
        u16x8 v7 = *(const u16x8*)&Acat[(size_t)s7 * 512 + 256 + lc];
#pragma unroll
        for (int i = 0; i < 8; i++)
            a[i] += ((b2f(v0[i]) + b2f(v1[i])) + (b2f(v2[i]) + b2f(v3[i]))) +
                    ((b2f(v4[i]) + b2f(v5[i])) + (b2f(v6[i]) + b2f(v7[i])));
    }
    for (; e + 3 < hi; e += 4) {
        int s0 = csr[e + 0], s1 = csr[e + 1], s2 = csr[e + 2], s3 = csr[e + 3];
        u16x8 v0 = *(const u16x8*)&Acat[(size_t)s0 * 512 + 256 + lc];
        u16x8 v1 = *(const u16x8*)&Acat[(size_t)s1 * 512 + 256 + lc];
        u16x8 v2 = *(const u16x8*)&Acat[(size_t)s2 * 512 + 256 + lc];
        u16x8 v3 = *(const u16x8*)&Acat[(size_t)s3 * 512 + 256 + lc];
#pragma unroll
        for (int i = 0; i < 8; i++)
            a[i] += (b2f(v0[i]) + b2f(v1[i])) + (b2f(v2[i]) + b2f(v3[i]));
    }
    for (; e < hi; e++) {
        int s0 = csr[e];
        u16x8 v0 = *(const u16x8*)&Acat[(size_t)s0 * 512 + 256 + lc];
#pragma unroll
        for (int i = 0; i < 8; i++) a[i] += b2f(v0[i]);
    }
#pragma unroll
    for (int i = 0; i < 8; i++) a[i] += __shfl_xor(a[i], 32);
    float sc = (deg > 0) ? 1.0f / (float)deg : 0.0f;
    if (half == 0) {
        u16x8 o;
#pragma unroll
        for (int i = 0; i < 8; i++) o[i] = f2b(a[i] * sc);
        *(u16x8*)&AcatW[(size_t)wid * 512 + lc] = o;
    }
}

// ---------------- MFMA GEMM (R8 4-buffer, counted vmcnt — best measured) ----
// 4-buffer LDS ring, stage tile t+2 at iter t, s_waitcnt vmcnt(8) + raw
// s_barrier: prefetches stay in flight across barriers.  Buffer staged at
// iter t was last read at iter t-2 -> two barriers separate read/overwrite.
template<int BF16_OUT>
__global__ __launch_bounds__(256)
void mfma_gemm_kernel(const u16* __restrict__ A, const u16* __restrict__ W,
                      const float* __restrict__ bias, void* __restrict__ Cout) {
    __shared__ u16 As[4][128 * 32];
    __shared__ u16 Bs[4][128 * 32];
    const int tid = threadIdx.x;
    const int l = tid & 63;
    const int wid = tid >> 6;
    const int wr = wid >> 1, wc = wid & 1;
    const int row0 = blockIdx.x * 128;
    const int col0 = blockIdx.y * 128;

    const u16* aptr[2];
    const u16* bptr[2];
#pragma unroll
    for (int i = 0; i < 2; i++) {
        int row = wid * 32 + i * 16 + (l >> 2);
        int kg = (l & 3) ^ ((row >> 1) & 3);   // pre-swizzled k-group (source side)
        int ra = row0 + row;
        if (ra > NN - 1) ra = NN - 1;
        aptr[i] = A + (size_t)ra * 512 + kg * 8;
        bptr[i] = W + (size_t)(col0 + row) * 512 + kg * 8;
    }

    f32x4 acc[4][4] = {};

#define STAGE(b, t)                                                          \
    do {                                                                     \
        _Pragma("unroll") for (int i_ = 0; i_ < 2; i_++) {                   \
            u16* al = &As[b][(wid * 32 + i_ * 16) * 32];                     \
            u16* bl = &Bs[b][(wid * 32 + i_ * 16) * 32];                     \
            gl16(aptr[i_] + (t) * 32, al);                                   \
            gl16(bptr[i_] + (t) * 32, bl);                                   \
        }                                                                    \
    } while (0)

    STAGE(0, 0);
    STAGE(1, 1);

    const int kq = l >> 4;
    const int sw = ((l & 15) >> 1) & 3;
#pragma unroll
    for (int t = 0; t < 16; t++) {
        if (t + 2 < 16) STAGE((t + 2) & 3, t + 2);

        if (t < 14)       asm volatile("s_waitcnt vmcnt(8)" ::: "memory");
        else if (t == 14) asm volatile("s_waitcnt vmcnt(4)" ::: "memory");
        else              asm volatile("s_waitcnt vmcnt(0)" ::: "memory");
        __builtin_amdgcn_s_barrier();
        __builtin_amdgcn_sched_barrier(0);

        short8 af[4], bf[4];
#pragma unroll
        for (int m = 0; m < 4; m++) {
            int row = wr * 64 + m * 16 + (l & 15);
            af[m] = *(const short8*)&As[t & 3][row * 32 + (kq ^ sw) * 8];
        }
#pragma unroll
        for (int n = 0; n < 4; n++) {
            int row = wc * 64 + n * 16 + (l & 15);
            bf[n] = *(const short8*)&Bs[t & 3][row * 32 + (kq ^ sw) * 8];
        }
#pragma unroll
        for (int m = 0; m < 4; m++)
#pragma unroll
            for (int n = 0; n < 4; n++)
                acc[m][n] = __builtin_amdgcn_mfma_f32_16x16x32_bf16(
                    af[m], bf[n], acc[m][n], 0, 0, 0);
    }
#undef STAGE

    // epilogue: C/D layout col = lane&15, row = (lane>>4)*4 + j
    const int cq = l >> 4;
    const int cc = l & 15;
#pragma unroll
    for (int m = 0; m < 4; m++) {
#pragma unroll
        for (int n = 0; n < 4; n++) {
            int c = col0 + wc * 64 + n * 16 + cc;
#pragma unroll
            for (int j = 0; j < 4; j++) {
                int r = row0 + wr * 64 + m * 16 + cq * 4 + j;
                if (r < NN) {
                    float v = acc[m][n][j] + bias[c];
                    if (BF16_OUT)
                        ((u16*)Cout)[(size_t)r * 256 + c] = f2b(v);
                    else
                        ((float*)Cout)[(size_t)r * 256 + c] = v;
                }
            }
        }
    }
}

// ---------------- per-column sum & sumsq for BN (bf16 input) ----------------
__global__ void colstats_kernel(const u16* __restrict__ h, float* __restrict__ stats) {
    int j = threadIdx.x;
    float s0 = 0.f, s1 = 0.f;
    for (int r = blockIdx.x; r < NN; r += gridDim.x) {
        float v = b2f(h[(size_t)r * 256 + j]);
        s0 += v;
        s1 += v * v;
    }
    atomicAdd(&stats[j], s0);
    atomicAdd(&stats[256 + j], s1);
}

// ---------------- BN + ReLU with inlined bnfin ----------------
__global__ void bnrelu_kernel(const u16* __restrict__ hb,
                              const float* __restrict__ stats,
                              const float* __restrict__ gamma,
                              const float* __restrict__ beta,
                              u16* __restrict__ Acat) {
    __shared__ float s_scale[256], s_shift[256];
    int t = threadIdx.x;
    {
        const float invN = 1.0f / (float)NN;
        float mu = stats[t] * invN;
        float var = stats[256 + t] * invN - mu * mu;
        float sc = gamma[t] * rsqrtf(var + 1e-5f);
        s_scale[t] = sc;
        s_shift[t] = beta[t] - mu * sc;
    }
    __syncthreads();
    int idx = blockIdx.x * 256 + t;
    int r = idx >> 5;
    int c8 = (idx & 31) * 8;
    u16x8 v = *(const u16x8*)&hb[(size_t)r * 256 + c8];
    u16x8 o;
#pragma unroll
    for (int i = 0; i < 8; i++) {
        float f = b2f(v[i]) * s_scale[c8 + i] + s_shift[c8 + i];
        o[i] = f2b(fmaxf(f, 0.f));
    }
    *(u16x8*)&Acat[(size_t)r * 512 + 256 + c8] = o;
}

// ---------------- row L2 normalize + fused column-sum ------------------
__global__ __launch_bounds__(512)
void l2norm_kernel(float* __restrict__ out, float* __restrict__ gsum) {
    __shared__ float sm[8 * 256];
    int wave = threadIdx.x >> 6;   // 0..7
    int lane = threadIdx.x & 63;
    float c0 = 0.f, c1 = 0.f, c2 = 0.f, c3 = 0.f;
    for (int r = blockIdx.x * 8 + wave; r < NN; r += gridDim.x * 8) {
        float4 v = *(float4*)&out[(size_t)r * 256 + lane * 4];
        float sq = v.x * v.x + v.y * v.y + v.z * v.z + v.w * v.w;
#pragma unroll
        for (int o = 32; o; o >>= 1) sq += __shfl_xor(sq, o);
        float invn = 1.0f / fmaxf(sqrtf(sq), 1e-12f);
        v.x *= invn; v.y *= invn; v.z *= invn; v.w *= invn;
        *(float4*)&out[(size_t)r * 256 + lane * 4] = v;
        c0 += v.x; c1 += v.y; c2 += v.z; c3 += v.w;
    }
    *(float4*)&sm[wave * 256 + lane * 4] = make_float4(c0, c1, c2, c3);
    __syncthreads();
    int t = threadIdx.x;
    if (t < 256) {
        float s = 0.f;
#pragma unroll
        for (int w = 0; w < 8; w++) s += sm[w * 256 + t];
        atomicAdd(&gsum[t], s);
    }
}

__global__ void graph_kernel(const float* __restrict__ gsum, float* __restrict__ gout) {
    __shared__ float wsum[4];
    int j = threadIdx.x;
    float v = gsum[j] * (1.0f / (float)NN);
    float sq = v * v;
#pragma unroll
    for (int o = 32; o; o >>= 1) sq += __shfl_xor(sq, o);
    if ((j & 63) == 0) wsum[j >> 6] = sq;
    __syncthreads();
    float tot = wsum[0] + wsum[1] + wsum[2] + wsum[3];
    gout[j] = v / fmaxf(sqrtf(tot), 1e-12f);
}

extern "C" void kernel_launch(void* const* d_in, const int* in_sizes, int n_in,
                              void* d_out, int out_size, void* d_ws, size_t ws_size,
                              hipStream_t stream) {
    const float* x      = (const float*)d_in[0];
    const float* W1_l   = (const float*)d_in[1];
    const float* b1_l   = (const float*)d_in[2];
    const float* W1_r   = (const float*)d_in[3];
    const float* W2_l   = (const float*)d_in[4];
    const float* b2_l   = (const float*)d_in[5];
    const float* W2_r   = (const float*)d_in[6];
    const float* gamma1 = (const float*)d_in[7];
    const float* beta1  = (const float*)d_in[8];
    const int*   eidx   = (const int*)d_in[9];
    const int* src = eidx;
    const int* dst = eidx + NE;

    char* wsb = (char*)d_ws;
    int*   deg   = (int*)(wsb + 0);
    int*   offs  = (int*)(wsb + 200000);
    int*   cur   = (int*)(wsb + 400004);
    int*   csr   = (int*)(wsb + 600004);
    int*   part  = (int*)(wsb + 3800064);
    int*   base  = (int*)(wsb + 3801088);
    float* stats = (float*)(wsb + 3802112);
    float* gsum  = (float*)(wsb + 3804160);
    u16*   Wcat1 = (u16*)(wsb + 3807232);
    u16*   Wcat2 = (u16*)(wsb + 4069376);
    u16*   hb    = (u16*)(wsb + 4331520);
    u16*   Acat  = (u16*)(wsb + 29931520);
    float* out   = (float*)d_out;
    float* gout  = out + (size_t)NN * 256;

    hipMemsetAsync(deg, 0, NN * sizeof(int), stream);
    hipMemsetAsync(stats, 0, 3072, stream);  // stats + gsum

    // xconv + wpack + degree in one launch (independent work, one dispatch)
    const int DEGB = (NE / 4 + 255) / 256;   // 782
    wxconv_kernel<<<12756 + DEGB, 256, 0, stream>>>(x, W1_l, W1_r, W2_l, W2_r,
                                                    dst, Acat, Wcat1, Wcat2, deg);

    scanA_kernel<<<SCB, 256, 0, stream>>>(deg, part);
    scanB_kernel<<<1, 256, 0, stream>>>(part, base, offs);
    scanC_kernel<<<SCB, 256, 0, stream>>>(deg, base, offs, cur);
    fill_kernel<<<(NE / 8 + 255) / 256, 256, 0, stream>>>(src, dst, cur, csr);

    dim3 ggrid((NN + 127) / 128, 2);

    // layer 1
    agg_kernel<<<12500, 256, 0, stream>>>(Acat, csr, offs, Acat);
    mfma_gemm_kernel<1><<<ggrid, 256, 0, stream>>>(Acat, Wcat1, b1_l, hb);
    colstats_kernel<<<512, 256, 0, stream>>>(hb, stats);
    bnrelu_kernel<<<6250, 256, 0, stream>>>(hb, stats, gamma1, beta1, Acat);

    // layer 2
    agg_kernel<<<12500, 256, 0, stream>>>(Acat, csr, offs, Acat);
    mfma_gemm_kernel<0><<<ggrid, 256, 0, stream>>>(Acat, Wcat2, b2_l, out);

    // outputs
    l2norm_kernel<<<1024, 512, 0, stream>>>(out, gsum);
    graph_kernel<<<1, 256, 0, stream>>>(gsum, gout);
}

// Round 15
// 382.049 us; speedup vs baseline: 1.2269x; 1.0140x over previous
//
#include <hip/hip_runtime.h>
#include <math.h>

#define NN 50000
#define NE 800000
#define D  256
#define SCB 196   // ceil(NN/256)
#define NB2 391   // ceil(NN/128) — row-blocks

typedef unsigned short u16;
typedef __attribute__((ext_vector_type(8))) short short8;
typedef __attribute__((ext_vector_type(8))) unsigned short u16x8;
typedef __attribute__((ext_vector_type(4))) float f32x4;

__device__ __forceinline__ u16 f2b(float f) {
    unsigned u = __float_as_uint(f);
    return (u16)((u + 0x7FFFu + ((u >> 16) & 1u)) >> 16);
}
__device__ __forceinline__ float b2f(u16 b) {
    return __uint_as_float(((unsigned)b) << 16);
}

__device__ __forceinline__ void gl16(const u16* g, u16* l) {
    __builtin_amdgcn_global_load_lds(
        (const __attribute__((address_space(1))) void*)g,
        (__attribute__((address_space(3))) void*)l, 16, 0, 0);
}

// ---------------- merged x-conv + weight pack + degree count ----------------
__global__ void wxconv_kernel(const float* __restrict__ x,
                              const float* __restrict__ W1l, const float* __restrict__ W1r,
                              const float* __restrict__ W2l, const float* __restrict__ W2r,
                              const int* __restrict__ dst,
                              u16* __restrict__ Acat,
                              u16* __restrict__ Wcat1, u16* __restrict__ Wcat2,
                              int* __restrict__ deg) {
    int b = blockIdx.x;
    if (b < 12500) {
        int idx = b * 256 + threadIdx.x;
        int r = idx >> 6;
        int c4 = (idx & 63) * 4;
        float4 v = *(const float4*)&x[(size_t)r * 256 + c4];
        ushort4 o;
        o.x = f2b(v.x); o.y = f2b(v.y); o.z = f2b(v.z); o.w = f2b(v.w);
        *(ushort4*)&Acat[(size_t)r * 512 + 256 + c4] = o;
    } else if (b < 12756) {
        int r = b - 12500;
        int j = threadIdx.x;
        Wcat1[r * 512 + j]       = f2b(W1l[r * 256 + j]);
        Wcat1[r * 512 + 256 + j] = f2b(W1r[r * 256 + j]);
        Wcat2[r * 512 + j]       = f2b(W2l[r * 256 + j]);
        Wcat2[r * 512 + 256 + j] = f2b(W2r[r * 256 + j]);
    } else {
        int e0 = ((b - 12756) * 256 + threadIdx.x) * 4;
        if (e0 + 3 < NE) {
            int4 d = *(const int4*)&dst[e0];
            atomicAdd(&deg[d.x], 1);
            atomicAdd(&deg[d.y], 1);
            atomicAdd(&deg[d.z], 1);
            atomicAdd(&deg[d.w], 1);
        } else {
            for (int e = e0; e < NE; e++) atomicAdd(&deg[dst[e]], 1);
        }
    }
}

// ---------------- CSR scan ----------------
__global__ void scanA_kernel(const int* __restrict__ deg, int* __restrict__ partial) {
    int t = threadIdx.x;
    int i = blockIdx.x * 256 + t;
    int v = (i < NN) ? deg[i] : 0;
#pragma unroll
    for (int o = 32; o; o >>= 1) v += __shfl_xor(v, o);
    __shared__ int sm[4];
    if ((t & 63) == 0) sm[t >> 6] = v;
    __syncthreads();
    if (t == 0) partial[blockIdx.x] = sm[0] + sm[1] + sm[2] + sm[3];
}

__global__ void scanB_kernel(const int* __restrict__ partial, int* __restrict__ base,
                             int* __restrict__ offs) {
    __shared__ int sm[256];
    int t = threadIdx.x;
    int v = (t < SCB) ? partial[t] : 0;
    sm[t] = v;
    __syncthreads();
    for (int off = 1; off < 256; off <<= 1) {
        int u = 0;
        if (t >= off) u = sm[t - off];
        __syncthreads();
        sm[t] += u;
        __syncthreads();
    }
    if (t < SCB) base[t] = sm[t] - v;
    if (t == 255) offs[NN] = sm[255];
}

__global__ void scanC_kernel(const int* __restrict__ deg, const int* __restrict__ base,
                             int* __restrict__ offs, int* __restrict__ cur) {
    __shared__ int sm[256];
    int t = threadIdx.x;
    int i = blockIdx.x * 256 + t;
    int v = (i < NN) ? deg[i] : 0;
    sm[t] = v;
    __syncthreads();
    for (int off = 1; off < 256; off <<= 1) {
        int u = 0;
        if (t >= off) u = sm[t - off];
        __syncthreads();
        sm[t] += u;
        __syncthreads();
    }
    int o = base[blockIdx.x] + sm[t] - v;
    if (i < NN) {
        offs[i] = o;
        cur[i] = o;
    }
}

__global__ void fill_kernel(const int* __restrict__ src, const int* __restrict__ dst,
                            int* __restrict__ cur, int* __restrict__ csr) {
    int e0 = (blockIdx.x * blockDim.x + threadIdx.x) * 8;
    if (e0 + 7 < NE) {
        int4 d0 = *(const int4*)&dst[e0];
        int4 d1 = *(const int4*)&dst[e0 + 4];
        int4 s0 = *(const int4*)&src[e0];
        int4 s1 = *(const int4*)&src[e0 + 4];
        int p0 = atomicAdd(&cur[d0.x], 1);
        int p1 = atomicAdd(&cur[d0.y], 1);
        int p2 = atomicAdd(&cur[d0.z], 1);
        int p3 = atomicAdd(&cur[d0.w], 1);
        int p4 = atomicAdd(&cur[d1.x], 1);
        int p5 = atomicAdd(&cur[d1.y], 1);
        int p6 = atomicAdd(&cur[d1.z], 1);
        int p7 = atomicAdd(&cur[d1.w], 1);
        csr[p0] = s0.x; csr[p1] = s0.y; csr[p2] = s0.z; csr[p3] = s0.w;
        csr[p4] = s1.x; csr[p5] = s1.y; csr[p6] = s1.z; csr[p7] = s1.w;
    } else {
        for (int e = e0; e < NE; e++) {
            int pos = atomicAdd(&cur[dst[e]], 1);
            csr[pos] = src[e];
        }
    }
}

// ---------------- mean aggregation: one wave per node, 8 gathers in flight --
__global__ __launch_bounds__(256)
void agg_kernel(const u16* __restrict__ Acat, const int* __restrict__ csr,
                const int* __restrict__ offs, u16* __restrict__ AcatW) {
    int wid = (blockIdx.x * blockDim.x + threadIdx.x) >> 6;
    int lane = threadIdx.x & 63;
    if (wid >= NN) return;
    int beg = offs[wid];
    int end = offs[wid + 1];
    int deg = end - beg;
    int half = lane >> 5;
    int lc = (lane & 31) * 8;
    int mid = beg + ((deg + 1) >> 1);
    int e  = half ? mid : beg;
    int hi = half ? end : mid;
    float a[8] = {0.f, 0.f, 0.f, 0.f, 0.f, 0.f, 0.f, 0.f};
    for (; e + 7 < hi; e += 8) {
        int s0 = csr[e + 0], s1 = csr[e + 1], s2 = csr[e + 2], s3 = csr[e + 3];
        int s4 = csr[e + 4], s5 = csr[e + 5], s6 = csr[e + 6], s7 = csr[e + 7];
        u16x8 v0 = *(const u16x8*)&Acat[(size_t)s0 * 512 + 256 + lc];
        u16x8 v1 = *(const u16x8*)&Acat[(size_t)s1 * 512 + 256 + lc];
        u16x8 v2 = *(const u16x8*)&Acat[(size_t)s2 * 512 + 256 + lc];
        u16x8 v3 = *(const u16x8*)&Acat[(size_t)s3 * 512 + 256 + lc];
        u16x8 v4 = *(const u16x8*)&Acat[(size_t)s4 * 512 + 256 + lc];
        u16x8 v5 = *(const u16x8*)&Acat[(size_t)s5 * 512 + 256 + lc];
        u16x8 v6 = *(const u16x8*)&Acat[(size_t)s6 * 512 + 256 + lc];
        u16x8 v7 = *(const u16x8*)&Acat[(size_t)s7 * 512 + 256 + lc];
#pragma unroll
        for (int i = 0; i < 8; i++)
            a[i] += ((b2f(v0[i]) + b2f(v1[i])) + (b2f(v2[i]) + b2f(v3[i]))) +
                    ((b2f(v4[i]) + b2f(v5[i])) + (b2f(v6[i]) + b2f(v7[i])));
    }
    for (; e + 3 < hi; e += 4) {
        int s0 = csr[e + 0], s1 = csr[e + 1], s2 = csr[e + 2], s3 = csr[e + 3];
        u16x8 v0 = *(const u16x8*)&Acat[(size_t)s0 * 512 + 256 + lc];
        u16x8 v1 = *(const u16x8*)&Acat[(size_t)s1 * 512 + 256 + lc];
        u16x8 v2 = *(const u16x8*)&Acat[(size_t)s2 * 512 + 256 + lc];
        u16x8 v3 = *(const u16x8*)&Acat[(size_t)s3 * 512 + 256 + lc];
#pragma unroll
        for (int i = 0; i < 8; i++)
            a[i] += (b2f(v0[i]) + b2f(v1[i])) + (b2f(v2[i]) + b2f(v3[i]));
    }
    for (; e < hi; e++) {
        int s0 = csr[e];
        u16x8 v0 = *(const u16x8*)&Acat[(size_t)s0 * 512 + 256 + lc];
#pragma unroll
        for (int i = 0; i < 8; i++) a[i] += b2f(v0[i]);
    }
#pragma unroll
    for (int i = 0; i < 8; i++) a[i] += __shfl_xor(a[i], 32);
    float sc = (deg > 0) ? 1.0f / (float)deg : 0.0f;
    if (half == 0) {
        u16x8 o;
#pragma unroll
        for (int i = 0; i < 8; i++) o[i] = f2b(a[i] * sc);
        *(u16x8*)&AcatW[(size_t)wid * 512 + lc] = o;
    }
}

// ---------------- GEMM-1 (R8 4-buffer, counted vmcnt — best measured) ------
__global__ __launch_bounds__(256)
void mfma_gemm_kernel(const u16* __restrict__ A, const u16* __restrict__ W,
                      const float* __restrict__ bias, u16* __restrict__ Cout) {
    __shared__ u16 As[4][128 * 32];
    __shared__ u16 Bs[4][128 * 32];
    const int tid = threadIdx.x;
    const int l = tid & 63;
    const int wid = tid >> 6;
    const int wr = wid >> 1, wc = wid & 1;
    const int row0 = blockIdx.x * 128;
    const int col0 = blockIdx.y * 128;

    const u16* aptr[2];
    const u16* bptr[2];
#pragma unroll
    for (int i = 0; i < 2; i++) {
        int row = wid * 32 + i * 16 + (l >> 2);
        int kg = (l & 3) ^ ((row >> 1) & 3);
        int ra = row0 + row;
        if (ra > NN - 1) ra = NN - 1;
        aptr[i] = A + (size_t)ra * 512 + kg * 8;
        bptr[i] = W + (size_t)(col0 + row) * 512 + kg * 8;
    }

    f32x4 acc[4][4] = {};

#define STAGE1(b, t)                                                         \
    do {                                                                     \
        _Pragma("unroll") for (int i_ = 0; i_ < 2; i_++) {                   \
            gl16(aptr[i_] + (t) * 32, &As[b][(wid * 32 + i_ * 16) * 32]);    \
            gl16(bptr[i_] + (t) * 32, &Bs[b][(wid * 32 + i_ * 16) * 32]);    \
        }                                                                    \
    } while (0)

    STAGE1(0, 0);
    STAGE1(1, 1);

    const int kq = l >> 4;
    const int sw = ((l & 15) >> 1) & 3;
#pragma unroll
    for (int t = 0; t < 16; t++) {
        if (t + 2 < 16) STAGE1((t + 2) & 3, t + 2);

        if (t < 14)       asm volatile("s_waitcnt vmcnt(8)" ::: "memory");
        else if (t == 14) asm volatile("s_waitcnt vmcnt(4)" ::: "memory");
        else              asm volatile("s_waitcnt vmcnt(0)" ::: "memory");
        __builtin_amdgcn_s_barrier();
        __builtin_amdgcn_sched_barrier(0);

        short8 af[4], bf[4];
#pragma unroll
        for (int m = 0; m < 4; m++) {
            int row = wr * 64 + m * 16 + (l & 15);
            af[m] = *(const short8*)&As[t & 3][row * 32 + (kq ^ sw) * 8];
        }
#pragma unroll
        for (int n = 0; n < 4; n++) {
            int row = wc * 64 + n * 16 + (l & 15);
            bf[n] = *(const short8*)&Bs[t & 3][row * 32 + (kq ^ sw) * 8];
        }
#pragma unroll
        for (int m = 0; m < 4; m++)
#pragma unroll
            for (int n = 0; n < 4; n++)
                acc[m][n] = __builtin_amdgcn_mfma_f32_16x16x32_bf16(
                    af[m], bf[n], acc[m][n], 0, 0, 0);
    }
#undef STAGE1

    const int cq = l >> 4;
    const int cc = l & 15;
#pragma unroll
    for (int m = 0; m < 4; m++) {
#pragma unroll
        for (int n = 0; n < 4; n++) {
            int c = col0 + wc * 64 + n * 16 + cc;
#pragma unroll
            for (int j = 0; j < 4; j++) {
                int r = row0 + wr * 64 + m * 16 + cq * 4 + j;
                if (r < NN)
                    Cout[(size_t)r * 256 + c] = f2b(acc[m][n][j] + bias[c]);
            }
        }
    }
}

// ---------------- GEMM-2: 128x256 tile + fused L2-normalize + colsum -------
// 3-buffer LDS ring (72 KB), wait->barrier->stage (R11-proven order).
// Epilogue: row sumsq (shfl over cc + LDS cross-wc combine), normalize in
// registers, single f32 write of node_emb, per-block colsum partials.
__global__ __launch_bounds__(256)
void gemm2_l2_kernel(const u16* __restrict__ A, const u16* __restrict__ W,
                     const float* __restrict__ bias, float* __restrict__ out,
                     float* __restrict__ colsum_part) {
    __shared__ u16 As[3][128 * 32];   // 24 KB
    __shared__ u16 Bs[3][256 * 32];   // 48 KB
    const int tid = threadIdx.x;
    const int l = tid & 63;
    const int wid = tid >> 6;
    const int wr = wid >> 1, wc = wid & 1;   // wave = rows [wr*64,+64) x cols [wc*128,+128)
    const int row0 = blockIdx.x * 128;

    // staging: wave stages A rows [wid*32,+32) (2 gl16) and B rows [wid*64,+64) (4 gl16)
    const u16* aptr[2];
    const u16* bptr[4];
#pragma unroll
    for (int i = 0; i < 2; i++) {
        int row = wid * 32 + i * 16 + (l >> 2);
        int kg = (l & 3) ^ ((row >> 1) & 3);
        int ra = row0 + row;
        if (ra > NN - 1) ra = NN - 1;
        aptr[i] = A + (size_t)ra * 512 + kg * 8;
    }
#pragma unroll
    for (int i = 0; i < 4; i++) {
        int row = wid * 64 + i * 16 + (l >> 2);
        int kg = (l & 3) ^ ((row >> 1) & 3);
        bptr[i] = W + (size_t)row * 512 + kg * 8;
    }

    f32x4 acc[4][8] = {};

#define STAGE2(b, t)                                                         \
    do {                                                                     \
        _Pragma("unroll") for (int i_ = 0; i_ < 2; i_++)                     \
            gl16(aptr[i_] + (t) * 32, &As[b][(wid * 32 + i_ * 16) * 32]);    \
        _Pragma("unroll") for (int i_ = 0; i_ < 4; i_++)                     \
            gl16(bptr[i_] + (t) * 32, &Bs[b][(wid * 64 + i_ * 16) * 32]);    \
    } while (0)

    STAGE2(0, 0);
    STAGE2(1, 1);

    const int kq = l >> 4;
    const int sw = ((l & 15) >> 1) & 3;
#pragma unroll
    for (int t = 0; t < 16; t++) {
        // own stage-t loads done; stage t+1 (6 loads) stays in flight
        if (t < 15) asm volatile("s_waitcnt vmcnt(6)" ::: "memory");
        else        asm volatile("s_waitcnt vmcnt(0)" ::: "memory");
        __builtin_amdgcn_s_barrier();
        __builtin_amdgcn_sched_barrier(0);

        if (t + 2 < 16) STAGE2((t + 2) % 3, t + 2);

        short8 af[4], bf[8];
#pragma unroll
        for (int m = 0; m < 4; m++) {
            int row = wr * 64 + m * 16 + (l & 15);
            af[m] = *(const short8*)&As[t % 3][row * 32 + (kq ^ sw) * 8];
        }
#pragma unroll
        for (int n = 0; n < 8; n++) {
            int row = wc * 128 + n * 16 + (l & 15);
            bf[n] = *(const short8*)&Bs[t % 3][row * 32 + (kq ^ sw) * 8];
        }
#pragma unroll
        for (int m = 0; m < 4; m++)
#pragma unroll
            for (int n = 0; n < 8; n++)
                acc[m][n] = __builtin_amdgcn_mfma_f32_16x16x32_bf16(
                    af[m], bf[n], acc[m][n], 0, 0, 0);
    }
#undef STAGE2

    // ---- epilogue ----
    // scratch in buffer 1 (last MFMA reads used buffer 0; barrier'd below)
    float* rowsq = (float*)&As[1][0];     // [2][128]  (wc-indexed)
    float* colp  = rowsq + 256;           // [2][256]  (wr-indexed)
    const int cq = l >> 4;
    const int cc = l & 15;

    // bias add + per-lane row sumsq (over this lane's 8 n-frags)
    float sq[4][4];
#pragma unroll
    for (int m = 0; m < 4; m++)
#pragma unroll
        for (int j = 0; j < 4; j++) {
            float s = 0.f;
#pragma unroll
            for (int n = 0; n < 8; n++) {
                float v = acc[m][n][j] + bias[wc * 128 + n * 16 + cc];
                acc[m][n][j] = v;
                s += v * v;
            }
            sq[m][j] = s;
        }
    // reduce over the 16 cc-lanes of this cq group
#pragma unroll
    for (int o = 1; o < 16; o <<= 1)
#pragma unroll
        for (int m = 0; m < 4; m++)
#pragma unroll
            for (int j = 0; j < 4; j++) sq[m][j] += __shfl_xor(sq[m][j], o);

    __syncthreads();   // all waves done with MFMA reads before scratch write
#pragma unroll
    for (int m = 0; m < 4; m++)
#pragma unroll
        for (int j = 0; j < 4; j++)
            if (cc == j) rowsq[wc * 128 + wr * 64 + m * 16 + cq * 4 + j] = sq[m][j];
    __syncthreads();

    float colpart[8] = {0.f, 0.f, 0.f, 0.f, 0.f, 0.f, 0.f, 0.f};
#pragma unroll
    for (int m = 0; m < 4; m++)
#pragma unroll
        for (int j = 0; j < 4; j++) {
            int rl = wr * 64 + m * 16 + cq * 4 + j;
            float s = rowsq[rl] + rowsq[128 + rl];
            float invn = 1.0f / fmaxf(sqrtf(s), 1e-12f);
            int r = row0 + rl;
            bool ok = (r < NN);
#pragma unroll
            for (int n = 0; n < 8; n++) {
                float vn = acc[m][n][j] * invn;
                if (ok) {
                    out[(size_t)r * 256 + wc * 128 + n * 16 + cc] = vn;
                    colpart[n] += vn;
                }
            }
        }
    // reduce colpart over cq groups (rows)
#pragma unroll
    for (int n = 0; n < 8; n++) {
        colpart[n] += __shfl_xor(colpart[n], 16);
        colpart[n] += __shfl_xor(colpart[n], 32);
    }
    if (l < 16) {
#pragma unroll
        for (int n = 0; n < 8; n++)
            colp[wr * 256 + wc * 128 + n * 16 + l] = colpart[n];
    }
    __syncthreads();
    if (tid < 256)
        colsum_part[(size_t)blockIdx.x * 256 + tid] = colp[tid] + colp[256 + tid];
}

// ---------------- per-column sum & sumsq for BN (bf16 input) ----------------
__global__ void colstats_kernel(const u16* __restrict__ h, float* __restrict__ stats) {
    int j = threadIdx.x;
    float s0 = 0.f, s1 = 0.f;
    for (int r = blockIdx.x; r < NN; r += gridDim.x) {
        float v = b2f(h[(size_t)r * 256 + j]);
        s0 += v;
        s1 += v * v;
    }
    atomicAdd(&stats[j], s0);
    atomicAdd(&stats[256 + j], s1);
}

// ---------------- BN + ReLU with inlined bnfin ----------------
__global__ void bnrelu_kernel(const u16* __restrict__ hb,
                              const float* __restrict__ stats,
                              const float* __restrict__ gamma,
                              const float* __restrict__ beta,
                              u16* __restrict__ Acat) {
    __shared__ float s_scale[256], s_shift[256];
    int t = threadIdx.x;
    {
        const float invN = 1.0f / (float)NN;
        float mu = stats[t] * invN;
        float var = stats[256 + t] * invN - mu * mu;
        float sc = gamma[t] * rsqrtf(var + 1e-5f);
        s_scale[t] = sc;
        s_shift[t] = beta[t] - mu * sc;
    }
    __syncthreads();
    int idx = blockIdx.x * 256 + t;
    int r = idx >> 5;
    int c8 = (idx & 31) * 8;
    u16x8 v = *(const u16x8*)&hb[(size_t)r * 256 + c8];
    u16x8 o;
#pragma unroll
    for (int i = 0; i < 8; i++) {
        float f = b2f(v[i]) * s_scale[c8 + i] + s_shift[c8 + i];
        o[i] = f2b(fmaxf(f, 0.f));
    }
    *(u16x8*)&Acat[(size_t)r * 512 + 256 + c8] = o;
}

// ---------------- graph embedding: reduce colsum partials + normalize ------
__global__ void graph_kernel(const float* __restrict__ colsum_part,
                             float* __restrict__ gout) {
    __shared__ float wsum[4];
    int j = threadIdx.x;
    float s = 0.f;
#pragma unroll 8
    for (int b = 0; b < NB2; b++) s += colsum_part[(size_t)b * 256 + j];
    float v = s * (1.0f / (float)NN);
    float sq = v * v;
#pragma unroll
    for (int o = 32; o; o >>= 1) sq += __shfl_xor(sq, o);
    if ((j & 63) == 0) wsum[j >> 6] = sq;
    __syncthreads();
    float tot = wsum[0] + wsum[1] + wsum[2] + wsum[3];
    gout[j] = v / fmaxf(sqrtf(tot), 1e-12f);
}

extern "C" void kernel_launch(void* const* d_in, const int* in_sizes, int n_in,
                              void* d_out, int out_size, void* d_ws, size_t ws_size,
                              hipStream_t stream) {
    const float* x      = (const float*)d_in[0];
    const float* W1_l   = (const float*)d_in[1];
    const float* b1_l   = (const float*)d_in[2];
    const float* W1_r   = (const float*)d_in[3];
    const float* W2_l   = (const float*)d_in[4];
    const float* b2_l   = (const float*)d_in[5];
    const float* W2_r   = (const float*)d_in[6];
    const float* gamma1 = (const float*)d_in[7];
    const float* beta1  = (const float*)d_in[8];
    const int*   eidx   = (const int*)d_in[9];
    const int* src = eidx;
    const int* dst = eidx + NE;

    char* wsb = (char*)d_ws;
    int*   deg    = (int*)(wsb + 0);
    int*   offs   = (int*)(wsb + 200000);
    int*   cur    = (int*)(wsb + 400004);
    int*   csr    = (int*)(wsb + 600004);      // 3.2 MB; reused as colsum_part
    float* cspart = (float*)(wsb + 600004);    // [391][256] f32 (after agg-2 done)
    int*   part   = (int*)(wsb + 3800064);
    int*   base   = (int*)(wsb + 3801088);
    float* stats  = (float*)(wsb + 3802112);
    u16*   Wcat1  = (u16*)(wsb + 3807232);
    u16*   Wcat2  = (u16*)(wsb + 4069376);
    u16*   hb     = (u16*)(wsb + 4331520);
    u16*   Acat   = (u16*)(wsb + 29931520);
    float* out    = (float*)d_out;
    float* gout   = out + (size_t)NN * 256;

    hipMemsetAsync(deg, 0, NN * sizeof(int), stream);
    hipMemsetAsync(stats, 0, 2048, stream);

    const int DEGB = (NE / 4 + 255) / 256;
    wxconv_kernel<<<12756 + DEGB, 256, 0, stream>>>(x, W1_l, W1_r, W2_l, W2_r,
                                                    dst, Acat, Wcat1, Wcat2, deg);

    scanA_kernel<<<SCB, 256, 0, stream>>>(deg, part);
    scanB_kernel<<<1, 256, 0, stream>>>(part, base, offs);
    scanC_kernel<<<SCB, 256, 0, stream>>>(deg, base, offs, cur);
    fill_kernel<<<(NE / 8 + 255) / 256, 256, 0, stream>>>(src, dst, cur, csr);

    dim3 ggrid(NB2, 2);

    // layer 1
    agg_kernel<<<12500, 256, 0, stream>>>(Acat, csr, offs, Acat);
    mfma_gemm_kernel<<<ggrid, 256, 0, stream>>>(Acat, Wcat1, b1_l, hb);
    colstats_kernel<<<512, 256, 0, stream>>>(hb, stats);
    bnrelu_kernel<<<6250, 256, 0, stream>>>(hb, stats, gamma1, beta1, Acat);

    // layer 2 (GEMM + fused L2-normalize + colsum partials)
    agg_kernel<<<12500, 256, 0, stream>>>(Acat, csr, offs, Acat);
    gemm2_l2_kernel<<<NB2, 256, 0, stream>>>(Acat, Wcat2, b2_l, out, cspart);

    // graph embedding
    graph_kernel<<<1, 256, 0, stream>>>(cspart, gout);
}

// Round 16
// 364.448 us; speedup vs baseline: 1.2862x; 1.0483x over previous
//
#include <hip/hip_runtime.h>
#include <math.h>

#define NN 50000
#define NE 800000
#define D  256
#define SCB 196   // ceil(NN/256)
#define NB2 391   // ceil(NN/128) — row-blocks

typedef unsigned short u16;
typedef __attribute__((ext_vector_type(8))) short short8;
typedef __attribute__((ext_vector_type(8))) unsigned short u16x8;
typedef __attribute__((ext_vector_type(4))) float f32x4;

__device__ __forceinline__ u16 f2b(float f) {
    unsigned u = __float_as_uint(f);
    return (u16)((u + 0x7FFFu + ((u >> 16) & 1u)) >> 16);
}
__device__ __forceinline__ float b2f(u16 b) {
    return __uint_as_float(((unsigned)b) << 16);
}

__device__ __forceinline__ void gl16(const u16* g, u16* l) {
    __builtin_amdgcn_global_load_lds(
        (const __attribute__((address_space(1))) void*)g,
        (__attribute__((address_space(3))) void*)l, 16, 0, 0);
}

// ---------------- merged x-conv + weight pack + degree count ----------------
__global__ void wxconv_kernel(const float* __restrict__ x,
                              const float* __restrict__ W1l, const float* __restrict__ W1r,
                              const float* __restrict__ W2l, const float* __restrict__ W2r,
                              const int* __restrict__ dst,
                              u16* __restrict__ Acat,
                              u16* __restrict__ Wcat1, u16* __restrict__ Wcat2,
                              int* __restrict__ deg) {
    int b = blockIdx.x;
    if (b < 12500) {
        int idx = b * 256 + threadIdx.x;
        int r = idx >> 6;
        int c4 = (idx & 63) * 4;
        float4 v = *(const float4*)&x[(size_t)r * 256 + c4];
        ushort4 o;
        o.x = f2b(v.x); o.y = f2b(v.y); o.z = f2b(v.z); o.w = f2b(v.w);
        *(ushort4*)&Acat[(size_t)r * 512 + 256 + c4] = o;
    } else if (b < 12756) {
        int r = b - 12500;
        int j = threadIdx.x;
        Wcat1[r * 512 + j]       = f2b(W1l[r * 256 + j]);
        Wcat1[r * 512 + 256 + j] = f2b(W1r[r * 256 + j]);
        Wcat2[r * 512 + j]       = f2b(W2l[r * 256 + j]);
        Wcat2[r * 512 + 256 + j] = f2b(W2r[r * 256 + j]);
    } else {
        int e0 = ((b - 12756) * 256 + threadIdx.x) * 4;
        if (e0 + 3 < NE) {
            int4 d = *(const int4*)&dst[e0];
            atomicAdd(&deg[d.x], 1);
            atomicAdd(&deg[d.y], 1);
            atomicAdd(&deg[d.z], 1);
            atomicAdd(&deg[d.w], 1);
        } else {
            for (int e = e0; e < NE; e++) atomicAdd(&deg[dst[e]], 1);
        }
    }
}

// ---------------- CSR scan ----------------
__global__ void scanA_kernel(const int* __restrict__ deg, int* __restrict__ partial) {
    int t = threadIdx.x;
    int i = blockIdx.x * 256 + t;
    int v = (i < NN) ? deg[i] : 0;
#pragma unroll
    for (int o = 32; o; o >>= 1) v += __shfl_xor(v, o);
    __shared__ int sm[4];
    if ((t & 63) == 0) sm[t >> 6] = v;
    __syncthreads();
    if (t == 0) partial[blockIdx.x] = sm[0] + sm[1] + sm[2] + sm[3];
}

__global__ void scanB_kernel(const int* __restrict__ partial, int* __restrict__ base,
                             int* __restrict__ offs) {
    __shared__ int sm[256];
    int t = threadIdx.x;
    int v = (t < SCB) ? partial[t] : 0;
    sm[t] = v;
    __syncthreads();
    for (int off = 1; off < 256; off <<= 1) {
        int u = 0;
        if (t >= off) u = sm[t - off];
        __syncthreads();
        sm[t] += u;
        __syncthreads();
    }
    if (t < SCB) base[t] = sm[t] - v;
    if (t == 255) offs[NN] = sm[255];
}

__global__ void scanC_kernel(const int* __restrict__ deg, const int* __restrict__ base,
                             int* __restrict__ offs, int* __restrict__ cur) {
    __shared__ int sm[256];
    int t = threadIdx.x;
    int i = blockIdx.x * 256 + t;
    int v = (i < NN) ? deg[i] : 0;
    sm[t] = v;
    __syncthreads();
    for (int off = 1; off < 256; off <<= 1) {
        int u = 0;
        if (t >= off) u = sm[t - off];
        __syncthreads();
        sm[t] += u;
        __syncthreads();
    }
    int o = base[blockIdx.x] + sm[t] - v;
    if (i < NN) {
        offs[i] = o;
        cur[i] = o;
    }
}

__global__ void fill_kernel(const int* __restrict__ src, const int* __restrict__ dst,
                            int* __restrict__ cur, int* __restrict__ csr) {
    int e0 = (blockIdx.x * blockDim.x + threadIdx.x) * 8;
    if (e0 + 7 < NE) {
        int4 d0 = *(const int4*)&dst[e0];
        int4 d1 = *(const int4*)&dst[e0 + 4];
        int4 s0 = *(const int4*)&src[e0];
        int4 s1 = *(const int4*)&src[e0 + 4];
        int p0 = atomicAdd(&cur[d0.x], 1);
        int p1 = atomicAdd(&cur[d0.y], 1);
        int p2 = atomicAdd(&cur[d0.z], 1);
        int p3 = atomicAdd(&cur[d0.w], 1);
        int p4 = atomicAdd(&cur[d1.x], 1);
        int p5 = atomicAdd(&cur[d1.y], 1);
        int p6 = atomicAdd(&cur[d1.z], 1);
        int p7 = atomicAdd(&cur[d1.w], 1);
        csr[p0] = s0.x; csr[p1] = s0.y; csr[p2] = s0.z; csr[p3] = s0.w;
        csr[p4] = s1.x; csr[p5] = s1.y; csr[p6] = s1.z; csr[p7] = s1.w;
    } else {
        for (int e = e0; e < NE; e++) {
            int pos = atomicAdd(&cur[dst[e]], 1);
            csr[pos] = src[e];
        }
    }
}

// ---------------- mean aggregation: one wave per node, 8 gathers in flight --
__global__ __launch_bounds__(256)
void agg_kernel(const u16* __restrict__ Acat, const int* __restrict__ csr,
                const int* __restrict__ offs, u16* __restrict__ AcatW) {
    int wid = (blockIdx.x * blockDim.x + threadIdx.x) >> 6;
    int lane = threadIdx.x & 63;
    if (wid >= NN) return;
    int beg = offs[wid];
    int end = offs[wid + 1];
    int deg = end - beg;
    int half = lane >> 5;
    int lc = (lane & 31) * 8;
    int mid = beg + ((deg + 1) >> 1);
    int e  = half ? mid : beg;
    int hi = half ? end : mid;
    float a[8] = {0.f, 0.f, 0.f, 0.f, 0.f, 0.f, 0.f, 0.f};
    for (; e + 7 < hi; e += 8) {
        int s0 = csr[e + 0], s1 = csr[e + 1], s2 = csr[e + 2], s3 = csr[e + 3];
        int s4 = csr[e + 4], s5 = csr[e + 5], s6 = csr[e + 6], s7 = csr[e + 7];
        u16x8 v0 = *(const u16x8*)&Acat[(size_t)s0 * 512 + 256 + lc];
        u16x8 v1 = *(const u16x8*)&Acat[(size_t)s1 * 512 + 256 + lc];
        u16x8 v2 = *(const u16x8*)&Acat[(size_t)s2 * 512 + 256 + lc];
        u16x8 v3 = *(const u16x8*)&Acat[(size_t)s3 * 512 + 256 + lc];
        u16x8 v4 = *(const u16x8*)&Acat[(size_t)s4 * 512 + 256 + lc];
        u16x8 v5 = *(const u16x8*)&Acat[(size_t)s5 * 512 + 256 + lc];
        u16x8 v6 = *(const u16x8*)&Acat[(size_t)s6 * 512 + 256 + lc];
        u16x8 v7 = *(const u16x8*)&Acat[(size_t)s7 * 512 + 256 + lc];
#pragma unroll
        for (int i = 0; i < 8; i++)
            a[i] += ((b2f(v0[i]) + b2f(v1[i])) + (b2f(v2[i]) + b2f(v3[i]))) +
                    ((b2f(v4[i]) + b2f(v5[i])) + (b2f(v6[i]) + b2f(v7[i])));
    }
    for (; e + 3 < hi; e += 4) {
        int s0 = csr[e + 0], s1 = csr[e + 1], s2 = csr[e + 2], s3 = csr[e + 3];
        u16x8 v0 = *(const u16x8*)&Acat[(size_t)s0 * 512 + 256 + lc];
        u16x8 v1 = *(const u16x8*)&Acat[(size_t)s1 * 512 + 256 + lc];
        u16x8 v2 = *(const u16x8*)&Acat[(size_t)s2 * 512 + 256 + lc];
        u16x8 v3 = *(const u16x8*)&Acat[(size_t)s3 * 512 + 256 + lc];
#pragma unroll
        for (int i = 0; i < 8; i++)
            a[i] += (b2f(v0[i]) + b2f(v1[i])) + (b2f(v2[i]) + b2f(v3[i]));
    }
    for (; e < hi; e++) {
        int s0 = csr[e];
        u16x8 v0 = *(const u16x8*)&Acat[(size_t)s0 * 512 + 256 + lc];
#pragma unroll
        for (int i = 0; i < 8; i++) a[i] += b2f(v0[i]);
    }
#pragma unroll
    for (int i = 0; i < 8; i++) a[i] += __shfl_xor(a[i], 32);
    float sc = (deg > 0) ? 1.0f / (float)deg : 0.0f;
    if (half == 0) {
        u16x8 o;
#pragma unroll
        for (int i = 0; i < 8; i++) o[i] = f2b(a[i] * sc);
        *(u16x8*)&AcatW[(size_t)wid * 512 + lc] = o;
    }
}

// ---------------- GEMM-1 (R8 4-buffer, counted vmcnt — best measured) ------
__global__ __launch_bounds__(256)
void mfma_gemm_kernel(const u16* __restrict__ A, const u16* __restrict__ W,
                      const float* __restrict__ bias, u16* __restrict__ Cout) {
    __shared__ u16 As[4][128 * 32];
    __shared__ u16 Bs[4][128 * 32];
    const int tid = threadIdx.x;
    const int l = tid & 63;
    const int wid = tid >> 6;
    const int wr = wid >> 1, wc = wid & 1;
    const int row0 = blockIdx.x * 128;
    const int col0 = blockIdx.y * 128;

    const u16* aptr[2];
    const u16* bptr[2];
#pragma unroll
    for (int i = 0; i < 2; i++) {
        int row = wid * 32 + i * 16 + (l >> 2);
        int kg = (l & 3) ^ ((row >> 1) & 3);
        int ra = row0 + row;
        if (ra > NN - 1) ra = NN - 1;
        aptr[i] = A + (size_t)ra * 512 + kg * 8;
        bptr[i] = W + (size_t)(col0 + row) * 512 + kg * 8;
    }

    f32x4 acc[4][4] = {};

#define STAGE1(b, t)                                                         \
    do {                                                                     \
        _Pragma("unroll") for (int i_ = 0; i_ < 2; i_++) {                   \
            gl16(aptr[i_] + (t) * 32, &As[b][(wid * 32 + i_ * 16) * 32]);    \
            gl16(bptr[i_] + (t) * 32, &Bs[b][(wid * 32 + i_ * 16) * 32]);    \
        }                                                                    \
    } while (0)

    STAGE1(0, 0);
    STAGE1(1, 1);

    const int kq = l >> 4;
    const int sw = ((l & 15) >> 1) & 3;
#pragma unroll
    for (int t = 0; t < 16; t++) {
        if (t + 2 < 16) STAGE1((t + 2) & 3, t + 2);

        if (t < 14)       asm volatile("s_waitcnt vmcnt(8)" ::: "memory");
        else if (t == 14) asm volatile("s_waitcnt vmcnt(4)" ::: "memory");
        else              asm volatile("s_waitcnt vmcnt(0)" ::: "memory");
        __builtin_amdgcn_s_barrier();
        __builtin_amdgcn_sched_barrier(0);

        short8 af[4], bf[4];
#pragma unroll
        for (int m = 0; m < 4; m++) {
            int row = wr * 64 + m * 16 + (l & 15);
            af[m] = *(const short8*)&As[t & 3][row * 32 + (kq ^ sw) * 8];
        }
#pragma unroll
        for (int n = 0; n < 4; n++) {
            int row = wc * 64 + n * 16 + (l & 15);
            bf[n] = *(const short8*)&Bs[t & 3][row * 32 + (kq ^ sw) * 8];
        }
#pragma unroll
        for (int m = 0; m < 4; m++)
#pragma unroll
            for (int n = 0; n < 4; n++)
                acc[m][n] = __builtin_amdgcn_mfma_f32_16x16x32_bf16(
                    af[m], bf[n], acc[m][n], 0, 0, 0);
    }
#undef STAGE1

    const int cq = l >> 4;
    const int cc = l & 15;
#pragma unroll
    for (int m = 0; m < 4; m++) {
#pragma unroll
        for (int n = 0; n < 4; n++) {
            int c = col0 + wc * 64 + n * 16 + cc;
#pragma unroll
            for (int j = 0; j < 4; j++) {
                int r = row0 + wr * 64 + m * 16 + cq * 4 + j;
                if (r < NN)
                    Cout[(size_t)r * 256 + c] = f2b(acc[m][n][j] + bias[c]);
            }
        }
    }
}

// ---------------- GEMM-2: 128x256 tile, 8 waves, fused L2-norm + colsum ----
// 512 threads: wave (wr,wc) owns rows [wr*64,+64) x cols [wc*64,+64).
// 3-buffer ring (72 KB), 3 gl16/wave/stage, counted vmcnt(3),
// wait->barrier->stage order.  Epilogue: rowsq[4][128] + colp[2][256] in
// the free As[1] buffer, normalize in registers, single f32 write.
__global__ __launch_bounds__(512)
void gemm2_l2_kernel(const u16* __restrict__ A, const u16* __restrict__ W,
                     const float* __restrict__ bias, float* __restrict__ out,
                     float* __restrict__ colsum_part) {
    __shared__ u16 As[3][128 * 32];   // 24 KB
    __shared__ u16 Bs[3][256 * 32];   // 48 KB
    const int tid = threadIdx.x;
    const int l = tid & 63;
    const int wid = tid >> 6;          // 0..7
    const int wr = wid >> 2;           // 0..1  (64 rows)
    const int wc = wid & 3;            // 0..3  (64 cols)
    const int row0 = blockIdx.x * 128;

    // staging: wave stages A rows [wid*16,+16) (1 gl16), B rows [wid*32,+32) (2 gl16)
    const u16* aptr;
    const u16* bptr[2];
    {
        int row = wid * 16 + (l >> 2);
        int kg = (l & 3) ^ ((row >> 1) & 3);
        int ra = row0 + row;
        if (ra > NN - 1) ra = NN - 1;
        aptr = A + (size_t)ra * 512 + kg * 8;
    }
#pragma unroll
    for (int i = 0; i < 2; i++) {
        int row = wid * 32 + i * 16 + (l >> 2);
        int kg = (l & 3) ^ ((row >> 1) & 3);
        bptr[i] = W + (size_t)row * 512 + kg * 8;
    }

    f32x4 acc[4][4] = {};

#define STAGE2(b, t)                                                         \
    do {                                                                     \
        gl16(aptr + (t) * 32, &As[b][(wid * 16) * 32]);                      \
        _Pragma("unroll") for (int i_ = 0; i_ < 2; i_++)                     \
            gl16(bptr[i_] + (t) * 32, &Bs[b][(wid * 32 + i_ * 16) * 32]);    \
    } while (0)

    STAGE2(0, 0);
    STAGE2(1, 1);

    const int kq = l >> 4;
    const int sw = ((l & 15) >> 1) & 3;
#pragma unroll
    for (int t = 0; t < 16; t++) {
        // own stage-t loads done; stage t+1 (3 loads) stays in flight
        if (t < 15) asm volatile("s_waitcnt vmcnt(3)" ::: "memory");
        else        asm volatile("s_waitcnt vmcnt(0)" ::: "memory");
        __builtin_amdgcn_s_barrier();
        __builtin_amdgcn_sched_barrier(0);

        if (t + 2 < 16) STAGE2((t + 2) % 3, t + 2);

        short8 af[4], bf[4];
#pragma unroll
        for (int m = 0; m < 4; m++) {
            int row = wr * 64 + m * 16 + (l & 15);
            af[m] = *(const short8*)&As[t % 3][row * 32 + (kq ^ sw) * 8];
        }
#pragma unroll
        for (int n = 0; n < 4; n++) {
            int row = wc * 64 + n * 16 + (l & 15);
            bf[n] = *(const short8*)&Bs[t % 3][row * 32 + (kq ^ sw) * 8];
        }
#pragma unroll
        for (int m = 0; m < 4; m++)
#pragma unroll
            for (int n = 0; n < 4; n++)
                acc[m][n] = __builtin_amdgcn_mfma_f32_16x16x32_bf16(
                    af[m], bf[n], acc[m][n], 0, 0, 0);
    }
#undef STAGE2

    // ---- epilogue ----
    float* rowsq = (float*)&As[1][0];   // [4][128] (wc-indexed)
    float* colp  = rowsq + 512;         // [2][256] (wr-indexed)
    const int cq = l >> 4;
    const int cc = l & 15;

    // bias add + per-lane row sumsq over this wave's 64 cols
    float sq[4][4];
#pragma unroll
    for (int m = 0; m < 4; m++)
#pragma unroll
        for (int j = 0; j < 4; j++) {
            float s = 0.f;
#pragma unroll
            for (int n = 0; n < 4; n++) {
                float v = acc[m][n][j] + bias[wc * 64 + n * 16 + cc];
                acc[m][n][j] = v;
                s += v * v;
            }
            sq[m][j] = s;
        }
#pragma unroll
    for (int o = 1; o < 16; o <<= 1)
#pragma unroll
        for (int m = 0; m < 4; m++)
#pragma unroll
            for (int j = 0; j < 4; j++) sq[m][j] += __shfl_xor(sq[m][j], o);

    __syncthreads();   // all waves done with LDS MFMA reads
#pragma unroll
    for (int m = 0; m < 4; m++)
#pragma unroll
        for (int j = 0; j < 4; j++)
            if (cc == j) rowsq[wc * 128 + wr * 64 + m * 16 + cq * 4 + j] = sq[m][j];
    __syncthreads();

    float colpart[4] = {0.f, 0.f, 0.f, 0.f};
#pragma unroll
    for (int m = 0; m < 4; m++)
#pragma unroll
        for (int j = 0; j < 4; j++) {
            int rl = wr * 64 + m * 16 + cq * 4 + j;
            float s = rowsq[rl] + rowsq[128 + rl] + rowsq[256 + rl] + rowsq[384 + rl];
            float invn = 1.0f / fmaxf(sqrtf(s), 1e-12f);
            int r = row0 + rl;
            bool ok = (r < NN);
#pragma unroll
            for (int n = 0; n < 4; n++) {
                float vn = acc[m][n][j] * invn;
                if (ok) {
                    out[(size_t)r * 256 + wc * 64 + n * 16 + cc] = vn;
                    colpart[n] += vn;
                }
            }
        }
#pragma unroll
    for (int n = 0; n < 4; n++) {
        colpart[n] += __shfl_xor(colpart[n], 16);
        colpart[n] += __shfl_xor(colpart[n], 32);
    }
    if (l < 16) {
#pragma unroll
        for (int n = 0; n < 4; n++)
            colp[wr * 256 + wc * 64 + n * 16 + l] = colpart[n];
    }
    __syncthreads();
    if (tid < 256)
        colsum_part[(size_t)blockIdx.x * 256 + tid] = colp[tid] + colp[256 + tid];
}

// ---------------- per-column sum & sumsq for BN (bf16 input) ----------------
__global__ void colstats_kernel(const u16* __restrict__ h, float* __restrict__ stats) {
    int j = threadIdx.x;
    float s0 = 0.f, s1 = 0.f;
    for (int r = blockIdx.x; r < NN; r += gridDim.x) {
        float v = b2f(h[(size_t)r * 256 + j]);
        s0 += v;
        s1 += v * v;
    }
    atomicAdd(&stats[j], s0);
    atomicAdd(&stats[256 + j], s1);
}

// ---------------- BN + ReLU with inlined bnfin ----------------
__global__ void bnrelu_kernel(const u16* __restrict__ hb,
                              const float* __restrict__ stats,
                              const float* __restrict__ gamma,
                              const float* __restrict__ beta,
                              u16* __restrict__ Acat) {
    __shared__ float s_scale[256], s_shift[256];
    int t = threadIdx.x;
    {
        const float invN = 1.0f / (float)NN;
        float mu = stats[t] * invN;
        float var = stats[256 + t] * invN - mu * mu;
        float sc = gamma[t] * rsqrtf(var + 1e-5f);
        s_scale[t] = sc;
        s_shift[t] = beta[t] - mu * sc;
    }
    __syncthreads();
    int idx = blockIdx.x * 256 + t;
    int r = idx >> 5;
    int c8 = (idx & 31) * 8;
    u16x8 v = *(const u16x8*)&hb[(size_t)r * 256 + c8];
    u16x8 o;
#pragma unroll
    for (int i = 0; i < 8; i++) {
        float f = b2f(v[i]) * s_scale[c8 + i] + s_shift[c8 + i];
        o[i] = f2b(fmaxf(f, 0.f));
    }
    *(u16x8*)&Acat[(size_t)r * 512 + 256 + c8] = o;
}

// ---------------- graph embedding: reduce colsum partials + normalize ------
__global__ void graph_kernel(const float* __restrict__ colsum_part,
                             float* __restrict__ gout) {
    __shared__ float wsum[4];
    int j = threadIdx.x;
    float s = 0.f;
#pragma unroll 8
    for (int b = 0; b < NB2; b++) s += colsum_part[(size_t)b * 256 + j];
    float v = s * (1.0f / (float)NN);
    float sq = v * v;
#pragma unroll
    for (int o = 32; o; o >>= 1) sq += __shfl_xor(sq, o);
    if ((j & 63) == 0) wsum[j >> 6] = sq;
    __syncthreads();
    float tot = wsum[0] + wsum[1] + wsum[2] + wsum[3];
    gout[j] = v / fmaxf(sqrtf(tot), 1e-12f);
}

extern "C" void kernel_launch(void* const* d_in, const int* in_sizes, int n_in,
                              void* d_out, int out_size, void* d_ws, size_t ws_size,
                              hipStream_t stream) {
    const float* x      = (const float*)d_in[0];
    const float* W1_l   = (const float*)d_in[1];
    const float* b1_l   = (const float*)d_in[2];
    const float* W1_r   = (const float*)d_in[3];
    const float* W2_l   = (const float*)d_in[4];
    const float* b2_l   = (const float*)d_in[5];
    const float* W2_r   = (const float*)d_in[6];
    const float* gamma1 = (const float*)d_in[7];
    const float* beta1  = (const float*)d_in[8];
    const int*   eidx   = (const int*)d_in[9];
    const int* src = eidx;
    const int* dst = eidx + NE;

    char* wsb = (char*)d_ws;
    int*   deg    = (int*)(wsb + 0);
    int*   offs   = (int*)(wsb + 200000);
    int*   cur    = (int*)(wsb + 400004);
    int*   csr    = (int*)(wsb + 600004);      // 3.2 MB; reused as colsum_part
    float* cspart = (float*)(wsb + 600004);    // [391][256] f32 (after agg-2 done)
    int*   part   = (int*)(wsb + 3800064);
    int*   base   = (int*)(wsb + 3801088);
    float* stats  = (float*)(wsb + 3802112);
    u16*   Wcat1  = (u16*)(wsb + 3807232);
    u16*   Wcat2  = (u16*)(wsb + 4069376);
    u16*   hb     = (u16*)(wsb + 4331520);
    u16*   Acat   = (u16*)(wsb + 29931520);
    float* out    = (float*)d_out;
    float* gout   = out + (size_t)NN * 256;

    hipMemsetAsync(deg, 0, NN * sizeof(int), stream);
    hipMemsetAsync(stats, 0, 2048, stream);

    const int DEGB = (NE / 4 + 255) / 256;
    wxconv_kernel<<<12756 + DEGB, 256, 0, stream>>>(x, W1_l, W1_r, W2_l, W2_r,
                                                    dst, Acat, Wcat1, Wcat2, deg);

    scanA_kernel<<<SCB, 256, 0, stream>>>(deg, part);
    scanB_kernel<<<1, 256, 0, stream>>>(part, base, offs);
    scanC_kernel<<<SCB, 256, 0, stream>>>(deg, base, offs, cur);
    fill_kernel<<<(NE / 8 + 255) / 256, 256, 0, stream>>>(src, dst, cur, csr);

    dim3 ggrid(NB2, 2);

    // layer 1
    agg_kernel<<<12500, 256, 0, stream>>>(Acat, csr, offs, Acat);
    mfma_gemm_kernel<<<ggrid, 256, 0, stream>>>(Acat, Wcat1, b1_l, hb);
    colstats_kernel<<<512, 256, 0, stream>>>(hb, stats);
    bnrelu_kernel<<<6250, 256, 0, stream>>>(hb, stats, gamma1, beta1, Acat);

    // layer 2 (GEMM + fused L2-normalize + colsum partials)
    agg_kernel<<<12500, 256, 0, stream>>>(Acat, csr, offs, Acat);
    gemm2_l2_kernel<<<NB2, 512, 0, stream>>>(Acat, Wcat2, b2_l, out, cspart);

    // graph embedding
    graph_kernel<<<1, 256, 0, stream>>>(cspart, gout);
}

// Round 17
// 327.025 us; speedup vs baseline: 1.4334x; 1.1144x over previous
//
#include <hip/hip_runtime.h>
#include <math.h>

#define NN 50000
#define NE 800000
#define D  256
#define SCB 196   // ceil(NN/256)
#define NB2 391   // ceil(NN/128) — row-blocks

typedef unsigned short u16;
typedef __attribute__((ext_vector_type(8))) short short8;
typedef __attribute__((ext_vector_type(8))) unsigned short u16x8;
typedef __attribute__((ext_vector_type(4))) float f32x4;

__device__ __forceinline__ u16 f2b(float f) {
    unsigned u = __float_as_uint(f);
    return (u16)((u + 0x7FFFu + ((u >> 16) & 1u)) >> 16);
}
__device__ __forceinline__ float b2f(u16 b) {
    return __uint_as_float(((unsigned)b) << 16);
}

__device__ __forceinline__ void gl16(const u16* g, u16* l) {
    __builtin_amdgcn_global_load_lds(
        (const __attribute__((address_space(1))) void*)g,
        (__attribute__((address_space(3))) void*)l, 16, 0, 0);
}

// ---------------- merged x-conv + weight pack + degree count ----------------
__global__ void wxconv_kernel(const float* __restrict__ x,
                              const float* __restrict__ W1l, const float* __restrict__ W1r,
                              const float* __restrict__ W2l, const float* __restrict__ W2r,
                              const int* __restrict__ dst,
                              u16* __restrict__ Acat,
                              u16* __restrict__ Wcat1, u16* __restrict__ Wcat2,
                              int* __restrict__ deg) {
    int b = blockIdx.x;
    if (b < 12500) {
        int idx = b * 256 + threadIdx.x;
        int r = idx >> 6;
        int c4 = (idx & 63) * 4;
        float4 v = *(const float4*)&x[(size_t)r * 256 + c4];
        ushort4 o;
        o.x = f2b(v.x); o.y = f2b(v.y); o.z = f2b(v.z); o.w = f2b(v.w);
        *(ushort4*)&Acat[(size_t)r * 512 + 256 + c4] = o;
    } else if (b < 12756) {
        int r = b - 12500;
        int j = threadIdx.x;
        Wcat1[r * 512 + j]       = f2b(W1l[r * 256 + j]);
        Wcat1[r * 512 + 256 + j] = f2b(W1r[r * 256 + j]);
        Wcat2[r * 512 + j]       = f2b(W2l[r * 256 + j]);
        Wcat2[r * 512 + 256 + j] = f2b(W2r[r * 256 + j]);
    } else {
        int e0 = ((b - 12756) * 256 + threadIdx.x) * 4;
        if (e0 + 3 < NE) {
            int4 d = *(const int4*)&dst[e0];
            atomicAdd(&deg[d.x], 1);
            atomicAdd(&deg[d.y], 1);
            atomicAdd(&deg[d.z], 1);
            atomicAdd(&deg[d.w], 1);
        } else {
            for (int e = e0; e < NE; e++) atomicAdd(&deg[dst[e]], 1);
        }
    }
}

// ---------------- CSR scan (scanB folded into scanC) ----------------
__global__ void scanA_kernel(const int* __restrict__ deg, int* __restrict__ partial) {
    int t = threadIdx.x;
    int i = blockIdx.x * 256 + t;
    int v = (i < NN) ? deg[i] : 0;
#pragma unroll
    for (int o = 32; o; o >>= 1) v += __shfl_xor(v, o);
    __shared__ int sm[4];
    if ((t & 63) == 0) sm[t >> 6] = v;
    __syncthreads();
    if (t == 0) partial[blockIdx.x] = sm[0] + sm[1] + sm[2] + sm[3];
}

// each block: local scan of block partials -> own base; also local scan of deg
__global__ void scanC_kernel(const int* __restrict__ deg, const int* __restrict__ partial,
                             int* __restrict__ offs, int* __restrict__ cur) {
    __shared__ int smp[256];
    __shared__ int sm[256];
    int t = threadIdx.x;
    // scan the per-block partials (196 values) locally
    int pv = (t < SCB) ? partial[t] : 0;
    smp[t] = pv;
    __syncthreads();
    for (int off = 1; off < 256; off <<= 1) {
        int u = 0;
        if (t >= off) u = smp[t - off];
        __syncthreads();
        smp[t] += u;
        __syncthreads();
    }
    int bid = blockIdx.x;
    int blockbase = (bid > 0) ? smp[bid - 1] : 0;
    if (bid == SCB - 1 && t == 255) offs[NN] = smp[255];

    int i = bid * 256 + t;
    int v = (i < NN) ? deg[i] : 0;
    sm[t] = v;
    __syncthreads();
    for (int off = 1; off < 256; off <<= 1) {
        int u = 0;
        if (t >= off) u = sm[t - off];
        __syncthreads();
        sm[t] += u;
        __syncthreads();
    }
    int o = blockbase + sm[t] - v;
    if (i < NN) {
        offs[i] = o;
        cur[i] = o;
    }
}

__global__ void fill_kernel(const int* __restrict__ src, const int* __restrict__ dst,
                            int* __restrict__ cur, int* __restrict__ csr) {
    int e0 = (blockIdx.x * blockDim.x + threadIdx.x) * 8;
    if (e0 + 7 < NE) {
        int4 d0 = *(const int4*)&dst[e0];
        int4 d1 = *(const int4*)&dst[e0 + 4];
        int4 s0 = *(const int4*)&src[e0];
        int4 s1 = *(const int4*)&src[e0 + 4];
        int p0 = atomicAdd(&cur[d0.x], 1);
        int p1 = atomicAdd(&cur[d0.y], 1);
        int p2 = atomicAdd(&cur[d0.z], 1);
        int p3 = atomicAdd(&cur[d0.w], 1);
        int p4 = atomicAdd(&cur[d1.x], 1);
        int p5 = atomicAdd(&cur[d1.y], 1);
        int p6 = atomicAdd(&cur[d1.z], 1);
        int p7 = atomicAdd(&cur[d1.w], 1);
        csr[p0] = s0.x; csr[p1] = s0.y; csr[p2] = s0.z; csr[p3] = s0.w;
        csr[p4] = s1.x; csr[p5] = s1.y; csr[p6] = s1.z; csr[p7] = s1.w;
    } else {
        for (int e = e0; e < NE; e++) {
            int pos = atomicAdd(&cur[dst[e]], 1);
            csr[pos] = src[e];
        }
    }
}

// ---------------- mean aggregation: one wave per node, 8 gathers in flight --
__global__ __launch_bounds__(256)
void agg_kernel(const u16* __restrict__ Acat, const int* __restrict__ csr,
                const int* __restrict__ offs, u16* __restrict__ AcatW) {
    int wid = (blockIdx.x * blockDim.x + threadIdx.x) >> 6;
    int lane = threadIdx.x & 63;
    if (wid >= NN) return;
    int beg = offs[wid];
    int end = offs[wid + 1];
    int deg = end - beg;
    int half = lane >> 5;
    int lc = (lane & 31) * 8;
    int mid = beg + ((deg + 1) >> 1);
    int e  = half ? mid : beg;
    int hi = half ? end : mid;
    float a[8] = {0.f, 0.f, 0.f, 0.f, 0.f, 0.f, 0.f, 0.f};
    for (; e + 7 < hi; e += 8) {
        int s0 = csr[e + 0], s1 = csr[e + 1], s2 = csr[e + 2], s3 = csr[e + 3];
        int s4 = csr[e + 4], s5 = csr[e + 5], s6 = csr[e + 6], s7 = csr[e + 7];
        u16x8 v0 = *(const u16x8*)&Acat[(size_t)s0 * 512 + 256 + lc];
        u16x8 v1 = *(const u16x8*)&Acat[(size_t)s1 * 512 + 256 + lc];
        u16x8 v2 = *(const u16x8*)&Acat[(size_t)s2 * 512 + 256 + lc];
        u16x8 v3 = *(const u16x8*)&Acat[(size_t)s3 * 512 + 256 + lc];
        u16x8 v4 = *(const u16x8*)&Acat[(size_t)s4 * 512 + 256 + lc];
        u16x8 v5 = *(const u16x8*)&Acat[(size_t)s5 * 512 + 256 + lc];
        u16x8 v6 = *(const u16x8*)&Acat[(size_t)s6 * 512 + 256 + lc];
        u16x8 v7 = *(const u16x8*)&Acat[(size_t)s7 * 512 + 256 + lc];
#pragma unroll
        for (int i = 0; i < 8; i++)
            a[i] += ((b2f(v0[i]) + b2f(v1[i])) + (b2f(v2[i]) + b2f(v3[i]))) +
                    ((b2f(v4[i]) + b2f(v5[i])) + (b2f(v6[i]) + b2f(v7[i])));
    }
    for (; e + 3 < hi; e += 4) {
        int s0 = csr[e + 0], s1 = csr[e + 1], s2 = csr[e + 2], s3 = csr[e + 3];
        u16x8 v0 = *(const u16x8*)&Acat[(size_t)s0 * 512 + 256 + lc];
        u16x8 v1 = *(const u16x8*)&Acat[(size_t)s1 * 512 + 256 + lc];
        u16x8 v2 = *(const u16x8*)&Acat[(size_t)s2 * 512 + 256 + lc];
        u16x8 v3 = *(const u16x8*)&Acat[(size_t)s3 * 512 + 256 + lc];
#pragma unroll
        for (int i = 0; i < 8; i++)
            a[i] += (b2f(v0[i]) + b2f(v1[i])) + (b2f(v2[i]) + b2f(v3[i]));
    }
    for (; e < hi; e++) {
        int s0 = csr[e];
        u16x8 v0 = *(const u16x8*)&Acat[(size_t)s0 * 512 + 256 + lc];
#pragma unroll
        for (int i = 0; i < 8; i++) a[i] += b2f(v0[i]);
    }
#pragma unroll
    for (int i = 0; i < 8; i++) a[i] += __shfl_xor(a[i], 32);
    float sc = (deg > 0) ? 1.0f / (float)deg : 0.0f;
    if (half == 0) {
        u16x8 o;
#pragma unroll
        for (int i = 0; i < 8; i++) o[i] = f2b(a[i] * sc);
        *(u16x8*)&AcatW[(size_t)wid * 512 + lc] = o;
    }
}

// ---------------- GEMM-1: 128x256 tile, 8 waves (gemm2 geometry, bf16 out) --
__global__ __launch_bounds__(512)
void mfma_gemm_kernel(const u16* __restrict__ A, const u16* __restrict__ W,
                      const float* __restrict__ bias, u16* __restrict__ Cout) {
    __shared__ u16 As[3][128 * 32];   // 24 KB
    __shared__ u16 Bs[3][256 * 32];   // 48 KB
    const int tid = threadIdx.x;
    const int l = tid & 63;
    const int wid = tid >> 6;          // 0..7
    const int wr = wid >> 2;           // 0..1
    const int wc = wid & 3;            // 0..3
    const int row0 = blockIdx.x * 128;

    const u16* aptr;
    const u16* bptr[2];
    {
        int row = wid * 16 + (l >> 2);
        int kg = (l & 3) ^ ((row >> 1) & 3);
        int ra = row0 + row;
        if (ra > NN - 1) ra = NN - 1;
        aptr = A + (size_t)ra * 512 + kg * 8;
    }
#pragma unroll
    for (int i = 0; i < 2; i++) {
        int row = wid * 32 + i * 16 + (l >> 2);
        int kg = (l & 3) ^ ((row >> 1) & 3);
        bptr[i] = W + (size_t)row * 512 + kg * 8;
    }

    f32x4 acc[4][4] = {};

#define STAGE1(b, t)                                                         \
    do {                                                                     \
        gl16(aptr + (t) * 32, &As[b][(wid * 16) * 32]);                      \
        _Pragma("unroll") for (int i_ = 0; i_ < 2; i_++)                     \
            gl16(bptr[i_] + (t) * 32, &Bs[b][(wid * 32 + i_ * 16) * 32]);    \
    } while (0)

    STAGE1(0, 0);
    STAGE1(1, 1);

    const int kq = l >> 4;
    const int sw = ((l & 15) >> 1) & 3;
#pragma unroll
    for (int t = 0; t < 16; t++) {
        if (t < 15) asm volatile("s_waitcnt vmcnt(3)" ::: "memory");
        else        asm volatile("s_waitcnt vmcnt(0)" ::: "memory");
        __builtin_amdgcn_s_barrier();
        __builtin_amdgcn_sched_barrier(0);

        if (t + 2 < 16) STAGE1((t + 2) % 3, t + 2);

        short8 af[4], bf[4];
#pragma unroll
        for (int m = 0; m < 4; m++) {
            int row = wr * 64 + m * 16 + (l & 15);
            af[m] = *(const short8*)&As[t % 3][row * 32 + (kq ^ sw) * 8];
        }
#pragma unroll
        for (int n = 0; n < 4; n++) {
            int row = wc * 64 + n * 16 + (l & 15);
            bf[n] = *(const short8*)&Bs[t % 3][row * 32 + (kq ^ sw) * 8];
        }
#pragma unroll
        for (int m = 0; m < 4; m++)
#pragma unroll
            for (int n = 0; n < 4; n++)
                acc[m][n] = __builtin_amdgcn_mfma_f32_16x16x32_bf16(
                    af[m], bf[n], acc[m][n], 0, 0, 0);
    }
#undef STAGE1

    const int cq = l >> 4;
    const int cc = l & 15;
#pragma unroll
    for (int m = 0; m < 4; m++) {
#pragma unroll
        for (int n = 0; n < 4; n++) {
            int c = wc * 64 + n * 16 + cc;
#pragma unroll
            for (int j = 0; j < 4; j++) {
                int r = row0 + wr * 64 + m * 16 + cq * 4 + j;
                if (r < NN)
                    Cout[(size_t)r * 256 + c] = f2b(acc[m][n][j] + bias[c]);
            }
        }
    }
}

// ---------------- GEMM-2: 128x256 tile, 8 waves, fused L2-norm + colsum ----
__global__ __launch_bounds__(512)
void gemm2_l2_kernel(const u16* __restrict__ A, const u16* __restrict__ W,
                     const float* __restrict__ bias, float* __restrict__ out,
                     float* __restrict__ colsum_part) {
    __shared__ u16 As[3][128 * 32];
    __shared__ u16 Bs[3][256 * 32];
    const int tid = threadIdx.x;
    const int l = tid & 63;
    const int wid = tid >> 6;
    const int wr = wid >> 2;
    const int wc = wid & 3;
    const int row0 = blockIdx.x * 128;

    const u16* aptr;
    const u16* bptr[2];
    {
        int row = wid * 16 + (l >> 2);
        int kg = (l & 3) ^ ((row >> 1) & 3);
        int ra = row0 + row;
        if (ra > NN - 1) ra = NN - 1;
        aptr = A + (size_t)ra * 512 + kg * 8;
    }
#pragma unroll
    for (int i = 0; i < 2; i++) {
        int row = wid * 32 + i * 16 + (l >> 2);
        int kg = (l & 3) ^ ((row >> 1) & 3);
        bptr[i] = W + (size_t)row * 512 + kg * 8;
    }

    f32x4 acc[4][4] = {};

#define STAGE2(b, t)                                                         \
    do {                                                                     \
        gl16(aptr + (t) * 32, &As[b][(wid * 16) * 32]);                      \
        _Pragma("unroll") for (int i_ = 0; i_ < 2; i_++)                     \
            gl16(bptr[i_] + (t) * 32, &Bs[b][(wid * 32 + i_ * 16) * 32]);    \
    } while (0)

    STAGE2(0, 0);
    STAGE2(1, 1);

    const int kq = l >> 4;
    const int sw = ((l & 15) >> 1) & 3;
#pragma unroll
    for (int t = 0; t < 16; t++) {
        if (t < 15) asm volatile("s_waitcnt vmcnt(3)" ::: "memory");
        else        asm volatile("s_waitcnt vmcnt(0)" ::: "memory");
        __builtin_amdgcn_s_barrier();
        __builtin_amdgcn_sched_barrier(0);

        if (t + 2 < 16) STAGE2((t + 2) % 3, t + 2);

        short8 af[4], bf[4];
#pragma unroll
        for (int m = 0; m < 4; m++) {
            int row = wr * 64 + m * 16 + (l & 15);
            af[m] = *(const short8*)&As[t % 3][row * 32 + (kq ^ sw) * 8];
        }
#pragma unroll
        for (int n = 0; n < 4; n++) {
            int row = wc * 64 + n * 16 + (l & 15);
            bf[n] = *(const short8*)&Bs[t % 3][row * 32 + (kq ^ sw) * 8];
        }
#pragma unroll
        for (int m = 0; m < 4; m++)
#pragma unroll
            for (int n = 0; n < 4; n++)
                acc[m][n] = __builtin_amdgcn_mfma_f32_16x16x32_bf16(
                    af[m], bf[n], acc[m][n], 0, 0, 0);
    }
#undef STAGE2

    // ---- epilogue ----
    float* rowsq = (float*)&As[1][0];   // [4][128]
    float* colp  = rowsq + 512;         // [2][256]
    const int cq = l >> 4;
    const int cc = l & 15;

    float sq[4][4];
#pragma unroll
    for (int m = 0; m < 4; m++)
#pragma unroll
        for (int j = 0; j < 4; j++) {
            float s = 0.f;
#pragma unroll
            for (int n = 0; n < 4; n++) {
                float v = acc[m][n][j] + bias[wc * 64 + n * 16 + cc];
                acc[m][n][j] = v;
                s += v * v;
            }
            sq[m][j] = s;
        }
#pragma unroll
    for (int o = 1; o < 16; o <<= 1)
#pragma unroll
        for (int m = 0; m < 4; m++)
#pragma unroll
            for (int j = 0; j < 4; j++) sq[m][j] += __shfl_xor(sq[m][j], o);

    __syncthreads();
#pragma unroll
    for (int m = 0; m < 4; m++)
#pragma unroll
        for (int j = 0; j < 4; j++)
            if (cc == j) rowsq[wc * 128 + wr * 64 + m * 16 + cq * 4 + j] = sq[m][j];
    __syncthreads();

    float colpart[4] = {0.f, 0.f, 0.f, 0.f};
#pragma unroll
    for (int m = 0; m < 4; m++)
#pragma unroll
        for (int j = 0; j < 4; j++) {
            int rl = wr * 64 + m * 16 + cq * 4 + j;
            float s = rowsq[rl] + rowsq[128 + rl] + rowsq[256 + rl] + rowsq[384 + rl];
            float invn = 1.0f / fmaxf(sqrtf(s), 1e-12f);
            int r = row0 + rl;
            bool ok = (r < NN);
#pragma unroll
            for (int n = 0; n < 4; n++) {
                float vn = acc[m][n][j] * invn;
                if (ok) {
                    out[(size_t)r * 256 + wc * 64 + n * 16 + cc] = vn;
                    colpart[n] += vn;
                }
            }
        }
#pragma unroll
    for (int n = 0; n < 4; n++) {
        colpart[n] += __shfl_xor(colpart[n], 16);
        colpart[n] += __shfl_xor(colpart[n], 32);
    }
    if (l < 16) {
#pragma unroll
        for (int n = 0; n < 4; n++)
            colp[wr * 256 + wc * 64 + n * 16 + l] = colpart[n];
    }
    __syncthreads();
    if (tid < 256)
        colsum_part[(size_t)blockIdx.x * 256 + tid] = colp[tid] + colp[256 + tid];
}

// ---------------- column stats: vectorized reads + 8-slot spread atomics ---
// thread t: cols (t&31)*8..+8, row offset t>>5; block covers 8 rows/iter.
__global__ __launch_bounds__(256)
void colstats_kernel(const u16* __restrict__ h, float* __restrict__ stats8) {
    __shared__ float red[8][512];
    int t = threadIdx.x;
    int cg = (t & 31) * 8;
    int rofs = t >> 5;
    float s0[8] = {}, s1[8] = {};
    for (int r = blockIdx.x * 8 + rofs; r < NN; r += gridDim.x * 8) {
        u16x8 v = *(const u16x8*)&h[(size_t)r * 256 + cg];
#pragma unroll
        for (int i = 0; i < 8; i++) {
            float f = b2f(v[i]);
            s0[i] += f;
            s1[i] += f * f;
        }
    }
#pragma unroll
    for (int i = 0; i < 8; i++) {
        red[rofs][cg + i] = s0[i];
        red[rofs][256 + cg + i] = s1[i];
    }
    __syncthreads();
    float* slot = stats8 + (blockIdx.x & 7) * 512;
    for (int k = t; k < 512; k += 256) {
        float s = red[0][k] + red[1][k] + red[2][k] + red[3][k] +
                  red[4][k] + red[5][k] + red[6][k] + red[7][k];
        atomicAdd(&slot[k], s);
    }
}

// ---------------- BN + ReLU (reads 8-slot stats) ----------------
__global__ void bnrelu_kernel(const u16* __restrict__ hb,
                              const float* __restrict__ stats8,
                              const float* __restrict__ gamma,
                              const float* __restrict__ beta,
                              u16* __restrict__ Acat) {
    __shared__ float s_scale[256], s_shift[256];
    int t = threadIdx.x;
    {
        float su = 0.f, sq = 0.f;
#pragma unroll
        for (int k = 0; k < 8; k++) {
            su += stats8[k * 512 + t];
            sq += stats8[k * 512 + 256 + t];
        }
        const float invN = 1.0f / (float)NN;
        float mu = su * invN;
        float var = sq * invN - mu * mu;
        float sc = gamma[t] * rsqrtf(var + 1e-5f);
        s_scale[t] = sc;
        s_shift[t] = beta[t] - mu * sc;
    }
    __syncthreads();
    int idx = blockIdx.x * 256 + t;
    int r = idx >> 5;
    int c8 = (idx & 31) * 8;
    u16x8 v = *(const u16x8*)&hb[(size_t)r * 256 + c8];
    u16x8 o;
#pragma unroll
    for (int i = 0; i < 8; i++) {
        float f = b2f(v[i]) * s_scale[c8 + i] + s_shift[c8 + i];
        o[i] = f2b(fmaxf(f, 0.f));
    }
    *(u16x8*)&Acat[(size_t)r * 512 + 256 + c8] = o;
}

// ---------------- graph embedding ----------------
__global__ void graph_kernel(const float* __restrict__ colsum_part,
                             float* __restrict__ gout) {
    __shared__ float wsum[4];
    int j = threadIdx.x;
    float s = 0.f;
#pragma unroll 8
    for (int b = 0; b < NB2; b++) s += colsum_part[(size_t)b * 256 + j];
    float v = s * (1.0f / (float)NN);
    float sq = v * v;
#pragma unroll
    for (int o = 32; o; o >>= 1) sq += __shfl_xor(sq, o);
    if ((j & 63) == 0) wsum[j >> 6] = sq;
    __syncthreads();
    float tot = wsum[0] + wsum[1] + wsum[2] + wsum[3];
    gout[j] = v / fmaxf(sqrtf(tot), 1e-12f);
}

extern "C" void kernel_launch(void* const* d_in, const int* in_sizes, int n_in,
                              void* d_out, int out_size, void* d_ws, size_t ws_size,
                              hipStream_t stream) {
    const float* x      = (const float*)d_in[0];
    const float* W1_l   = (const float*)d_in[1];
    const float* b1_l   = (const float*)d_in[2];
    const float* W1_r   = (const float*)d_in[3];
    const float* W2_l   = (const float*)d_in[4];
    const float* b2_l   = (const float*)d_in[5];
    const float* W2_r   = (const float*)d_in[6];
    const float* gamma1 = (const float*)d_in[7];
    const float* beta1  = (const float*)d_in[8];
    const int*   eidx   = (const int*)d_in[9];
    const int* src = eidx;
    const int* dst = eidx + NE;

    char* wsb = (char*)d_ws;
    int*   deg    = (int*)(wsb + 0);
    int*   offs   = (int*)(wsb + 200000);
    int*   cur    = (int*)(wsb + 400004);      // dead after fill; reused as stats8
    float* stats8 = (float*)(wsb + 400004);    // [8][512] f32 = 16 KB
    int*   csr    = (int*)(wsb + 600004);      // dead after agg-2; reused as cspart
    float* cspart = (float*)(wsb + 600004);    // [391][256] f32
    int*   part   = (int*)(wsb + 3800064);
    u16*   Wcat1  = (u16*)(wsb + 3807232);
    u16*   Wcat2  = (u16*)(wsb + 4069376);
    u16*   hb     = (u16*)(wsb + 4331520);
    u16*   Acat   = (u16*)(wsb + 29931520);
    float* out    = (float*)d_out;
    float* gout   = out + (size_t)NN * 256;

    hipMemsetAsync(deg, 0, NN * sizeof(int), stream);

    const int DEGB = (NE / 4 + 255) / 256;
    wxconv_kernel<<<12756 + DEGB, 256, 0, stream>>>(x, W1_l, W1_r, W2_l, W2_r,
                                                    dst, Acat, Wcat1, Wcat2, deg);

    scanA_kernel<<<SCB, 256, 0, stream>>>(deg, part);
    scanC_kernel<<<SCB, 256, 0, stream>>>(deg, part, offs, cur);
    fill_kernel<<<(NE / 8 + 255) / 256, 256, 0, stream>>>(src, dst, cur, csr);
    // cur is dead now; zero stats8 in its place
    hipMemsetAsync(stats8, 0, 16384, stream);

    // layer 1
    agg_kernel<<<12500, 256, 0, stream>>>(Acat, csr, offs, Acat);
    mfma_gemm_kernel<<<NB2, 512, 0, stream>>>(Acat, Wcat1, b1_l, hb);
    colstats_kernel<<<256, 256, 0, stream>>>(hb, stats8);
    bnrelu_kernel<<<6250, 256, 0, stream>>>(hb, stats8, gamma1, beta1, Acat);

    // layer 2 (GEMM + fused L2-normalize + colsum partials)
    agg_kernel<<<12500, 256, 0, stream>>>(Acat, csr, offs, Acat);
    gemm2_l2_kernel<<<NB2, 512, 0, stream>>>(Acat, Wcat2, b2_l, out, cspart);

    // graph embedding
    graph_kernel<<<1, 256, 0, stream>>>(cspart, gout);
}